// Round 1
// baseline (9036.282 us; speedup 1.0000x reference)
//
#include <hip/hip_runtime.h>
#include <type_traits>

// ---------------------------------------------------------------------------
// ProteinGCNNet: 3x GCNConv (self-loops, sym-norm) + mean-pool + 2 FC layers
// fp32 throughout. Aggregation = init-with-self-loop + atomic edge scatter.
// ---------------------------------------------------------------------------

static __host__ __device__ inline int cdiv(int a, int b) { return (a + b - 1) / b; }

template <int V> struct VecT;
template <> struct VecT<2> { using T = float2; };
template <> struct VecT<4> { using T = float4; };

// ---- degree / norm ---------------------------------------------------------
__global__ void k_init_deg(float* deg, int n) {
    int i = blockIdx.x * blockDim.x + threadIdx.x;
    if (i < n) deg[i] = 1.0f;  // self-loop contributes 1
}
__global__ void k_count_deg(const int* __restrict__ col, float* deg, int e) {
    int i = blockIdx.x * blockDim.x + threadIdx.x;
    if (i < e) atomicAdd(&deg[col[i]], 1.0f);
}
__global__ void k_dinv(float* deg, int n) {
    int i = blockIdx.x * blockDim.x + threadIdx.x;
    if (i < n) deg[i] = rsqrtf(deg[i]);  // deg >= 1 always (self-loop)
}
__global__ void k_norm(const int* __restrict__ row, const int* __restrict__ col,
                       const float* __restrict__ dinv, float* __restrict__ norm, int e) {
    int i = blockIdx.x * blockDim.x + threadIdx.x;
    if (i < e) norm[i] = dinv[row[i]] * dinv[col[i]];
}

// ---- node-feature GEMM: out[n, FOUT] = act(in)[n, K] @ W[K, FOUT] ----------
// ACT: in-element -> max(in + bias[k], 0)   (fused bias+relu of previous layer)
template <int K, int FOUT, int VEC, bool ACT>
__global__ void k_gemm(const float* __restrict__ in, const float* __restrict__ W,
                       const float* __restrict__ bias, float* __restrict__ out, int n) {
    using VT = typename VecT<VEC>::T;
    constexpr int CH = FOUT / VEC;
    int idx = blockIdx.x * blockDim.x + threadIdx.x;
    if (idx >= n * CH) return;
    int node = idx / CH;
    int c = idx - node * CH;
    const float* inrow = in + (long long)node * K;
    const float* wp = W + c * VEC;
    float acc[VEC];
#pragma unroll
    for (int j = 0; j < VEC; j++) acc[j] = 0.f;
    for (int k = 0; k < K; k++) {
        float a = inrow[k];
        if (ACT) a = fmaxf(a + bias[k], 0.f);
        VT w = *reinterpret_cast<const VT*>(wp + k * FOUT);
        acc[0] += a * w.x;
        acc[1] += a * w.y;
        if constexpr (VEC == 4) {
            acc[2] += a * w.z;
            acc[3] += a * w.w;
        }
    }
    VT o;
    o.x = acc[0]; o.y = acc[1];
    if constexpr (VEC == 4) { o.z = acc[2]; o.w = acc[3]; }
    *reinterpret_cast<VT*>(out + (long long)node * FOUT + c * VEC) = o;
}

// ---- aggregation init with self-loop term: agg[i] = h[i] * dinv[i]^2 -------
template <int F, int VEC>
__global__ void k_selfloop(const float* __restrict__ h, const float* __restrict__ dinv,
                           float* __restrict__ agg, int n) {
    using VT = typename VecT<VEC>::T;
    constexpr int CH = F / VEC;
    int idx = blockIdx.x * blockDim.x + threadIdx.x;
    if (idx >= n * CH) return;
    int node = idx / CH;
    int c = idx - node * CH;
    float s = dinv[node];
    s = s * s;
    VT v = *reinterpret_cast<const VT*>(h + (long long)node * F + c * VEC);
    v.x *= s; v.y *= s;
    if constexpr (VEC == 4) { v.z *= s; v.w *= s; }
    *reinterpret_cast<VT*>(agg + (long long)node * F + c * VEC) = v;
}

// ---- edge scatter: agg[col] += h[row] * norm[e]  (atomic) ------------------
template <int F, int VEC>
__global__ void k_scatter(const int* __restrict__ row, const int* __restrict__ col,
                          const float* __restrict__ norm, const float* __restrict__ h,
                          float* agg, int e) {
    using VT = typename VecT<VEC>::T;
    constexpr int CH = F / VEC;
    int idx = blockIdx.x * blockDim.x + threadIdx.x;
    if (idx >= e * CH) return;
    int ed = idx / CH;
    int c = idx - ed * CH;
    int r = row[ed];
    int cl = col[ed];
    float s = norm[ed];
    VT v = *reinterpret_cast<const VT*>(h + (long long)r * F + c * VEC);
    float* dst = agg + (long long)cl * F + c * VEC;
    atomicAdd(dst + 0, v.x * s);
    atomicAdd(dst + 1, v.y * s);
    if constexpr (VEC == 4) {
        atomicAdd(dst + 2, v.z * s);
        atomicAdd(dst + 3, v.w * s);
    }
}

// ---- per-graph boundaries (batch is sorted ascending) ----------------------
__global__ void k_init_start(int* start, int n, int g) {
    int i = blockIdx.x * blockDim.x + threadIdx.x;
    if (i <= g) start[i] = n;
}
__global__ void k_find_start(const int* __restrict__ batch, int* start, int n) {
    int i = blockIdx.x * blockDim.x + threadIdx.x;
    if (i >= n) return;
    int b = batch[i];
    int bp = (i == 0) ? -1 : batch[i - 1];
    for (int g = bp + 1; g <= b; g++) start[g] = i;
}

// ---- mean pool with fused relu(agg + b3) -----------------------------------
template <int F>
__global__ void k_pool(const float* __restrict__ agg, const float* __restrict__ bias,
                       const int* __restrict__ start, float* __restrict__ pooled) {
    int g = blockIdx.x;
    int f = threadIdx.x;
    if (f >= F) return;
    int s = start[g], e = start[g + 1];
    float b = bias[f];
    float acc = 0.f;
    for (int nd = s; nd < e; nd++)
        acc += fmaxf(agg[(long long)nd * F + f] + b, 0.f);
    float cnt = (float)(e - s);
    pooled[g * F + f] = acc / fmaxf(cnt, 1.0f);
}

// ---- FC layers -------------------------------------------------------------
// g[256,1024] = relu(P[256,216] @ Wf1[216,1024] + bf1)
__global__ void k_fc1(const float* __restrict__ P, const float* __restrict__ W,
                      const float* __restrict__ bias, float* __restrict__ out) {
    int row = blockIdx.x >> 2;
    int o = (blockIdx.x & 3) * 256 + threadIdx.x;
    __shared__ float prow[216];
    if (threadIdx.x < 216) prow[threadIdx.x] = P[row * 216 + threadIdx.x];
    __syncthreads();
    float acc = bias[o];
    for (int k = 0; k < 216; k++) acc += prow[k] * W[k * 1024 + o];
    out[row * 1024 + o] = fmaxf(acc, 0.f);
}
// out[256,128] = g[256,1024] @ Wf2[1024,128] + bf2
__global__ void k_fc2(const float* __restrict__ G, const float* __restrict__ W,
                      const float* __restrict__ bias, float* __restrict__ out) {
    int row = blockIdx.x;
    int o = threadIdx.x;  // 128 threads
    __shared__ float grow[1024];
    for (int k = threadIdx.x; k < 1024; k += 128) grow[k] = G[row * 1024 + k];
    __syncthreads();
    float acc = bias[o];
    for (int k = 0; k < 1024; k++) acc += grow[k] * W[k * 128 + o];
    out[row * 128 + o] = acc;
}

// ---------------------------------------------------------------------------
extern "C" void kernel_launch(void* const* d_in, const int* in_sizes, int n_in,
                              void* d_out, int out_size, void* d_ws, size_t ws_size,
                              hipStream_t stream) {
    const float* x     = (const float*)d_in[0];
    const int*   ei    = (const int*)d_in[1];
    const int*   batch = (const int*)d_in[2];
    const float* W1  = (const float*)d_in[3];
    const float* b1  = (const float*)d_in[4];
    const float* W2  = (const float*)d_in[5];
    const float* b2  = (const float*)d_in[6];
    const float* W3  = (const float*)d_in[7];
    const float* b3  = (const float*)d_in[8];
    const float* Wf1 = (const float*)d_in[9];
    const float* bf1 = (const float*)d_in[10];
    const float* Wf2 = (const float*)d_in[11];
    const float* bf2 = (const float*)d_in[12];
    float* out = (float*)d_out;

    const int N = in_sizes[0] / 54;   // 100000
    const int E = in_sizes[1] / 2;    // 1600000
    const int G = 256;
    const int* row = ei;
    const int* col = ei + E;

    // workspace carve-up (256B aligned chunks)
    char* ws = (char*)d_ws;
    size_t off = 0;
    auto carve = [&](size_t bytes) {
        void* p = ws + off;
        off += (bytes + 255) & ~(size_t)255;
        return p;
    };
    float* dinv   = (float*)carve((size_t)N * 4);            // degree -> dinv in place
    float* norm   = (float*)carve((size_t)E * 4);
    float* bufA   = (float*)carve((size_t)N * 216 * 4);      // h (gemm out)
    float* bufB   = (float*)carve((size_t)N * 216 * 4);      // agg
    float* pooled = (float*)carve((size_t)G * 216 * 4);
    float* gbuf   = (float*)carve((size_t)G * 1024 * 4);
    int*   start  = (int*)carve((size_t)(G + 1) * 4);

    const int T = 256;

    // degrees + norm
    k_init_deg<<<cdiv(N, T), T, 0, stream>>>(dinv, N);
    k_count_deg<<<cdiv(E, T), T, 0, stream>>>(col, dinv, E);
    k_dinv<<<cdiv(N, T), T, 0, stream>>>(dinv, N);
    k_norm<<<cdiv(E, T), T, 0, stream>>>(row, col, dinv, norm, E);

    // graph boundaries
    k_init_start<<<cdiv(G + 1, T), T, 0, stream>>>(start, N, G);
    k_find_start<<<cdiv(N, T), T, 0, stream>>>(batch, start, N);

    // ---- layer 1: h = x @ W1 ; agg = scatter(h * norm) ----
    k_gemm<54, 54, 2, false><<<cdiv(N * 27, T), T, 0, stream>>>(x, W1, nullptr, bufA, N);
    k_selfloop<54, 2><<<cdiv(N * 27, T), T, 0, stream>>>(bufA, dinv, bufB, N);
    k_scatter<54, 2><<<cdiv(E * 27, T), T, 0, stream>>>(row, col, norm, bufA, bufB, E);

    // ---- layer 2: h = relu(agg1 + b1) @ W2 ----
    k_gemm<54, 108, 4, true><<<cdiv(N * 27, T), T, 0, stream>>>(bufB, W2, b1, bufA, N);
    k_selfloop<108, 4><<<cdiv(N * 27, T), T, 0, stream>>>(bufA, dinv, bufB, N);
    k_scatter<108, 4><<<cdiv(E * 27, T), T, 0, stream>>>(row, col, norm, bufA, bufB, E);

    // ---- layer 3: h = relu(agg2 + b2) @ W3 ----
    k_gemm<108, 216, 4, true><<<cdiv(N * 54, T), T, 0, stream>>>(bufB, W3, b2, bufA, N);
    k_selfloop<216, 4><<<cdiv(N * 54, T), T, 0, stream>>>(bufA, dinv, bufB, N);
    k_scatter<216, 4><<<cdiv(E * 54, T), T, 0, stream>>>(row, col, norm, bufA, bufB, E);

    // ---- mean pool (fused relu(agg3 + b3)) ----
    k_pool<216><<<G, T, 0, stream>>>(bufB, b3, start, pooled);

    // ---- FC head ----
    k_fc1<<<G * 4, T, 0, stream>>>(pooled, Wf1, bf1, gbuf);
    k_fc2<<<G, 128, 0, stream>>>(gbuf, Wf2, bf2, out);
}

// Round 2
// 1367.964 us; speedup vs baseline: 6.6056x; 6.6056x over previous
//
#include <hip/hip_runtime.h>

// ---------------------------------------------------------------------------
// ProteinGCNNet: 3x GCNConv + mean-pool + 2 FC layers, fp32.
// Round 2: (1) aggregate-then-GEMM reorder (A_hat(XW) == (A_hat X)W),
//          (2) CSR gather aggregation (no fp32 atomics).
// ---------------------------------------------------------------------------

static __host__ __device__ inline int cdiv(int a, int b) { return (a + b - 1) / b; }

// ---- zero int arrays -------------------------------------------------------
__global__ void k_zero_int(int* p, int n) {
    int i = blockIdx.x * blockDim.x + threadIdx.x;
    if (i < n) p[i] = 0;
}

// ---- in-degree histogram ---------------------------------------------------
__global__ void k_count(const int* __restrict__ col, int* counts, int e) {
    int i = blockIdx.x * blockDim.x + threadIdx.x;
    if (i < e) atomicAdd(&counts[col[i]], 1);
}

// ---- dinv[i] = rsqrt(counts[i] + 1)  (self-loop adds 1; deg >= 1 always) ---
__global__ void k_dinv(const int* __restrict__ counts, float* __restrict__ dinv, int n) {
    int i = blockIdx.x * blockDim.x + threadIdx.x;
    if (i < n) dinv[i] = rsqrtf((float)(counts[i] + 1));
}

// ---- prefix scan of counts -> rowptr (exclusive), chunked ------------------
// chunk = 1024 elements per 256-thread block (4/thread)
__global__ void k_scan1(const int* __restrict__ counts, int* __restrict__ rowptr,
                        int* __restrict__ chunkSums, int n) {
    __shared__ int lds[256];
    int b = blockIdx.x, t = threadIdx.x;
    int base = b * 1024 + t * 4;
    int v[4], s = 0;
#pragma unroll
    for (int j = 0; j < 4; j++) {
        v[j] = (base + j < n) ? counts[base + j] : 0;
        s += v[j];
    }
    lds[t] = s;
    __syncthreads();
    for (int off = 1; off < 256; off <<= 1) {
        int x = lds[t];
        int y = (t >= off) ? lds[t - off] : 0;
        __syncthreads();
        lds[t] = x + y;
        __syncthreads();
    }
    int p = lds[t] - s;  // exclusive prefix of this thread within chunk
#pragma unroll
    for (int j = 0; j < 4; j++) {
        if (base + j < n) rowptr[base + j] = p;
        p += v[j];
    }
    if (t == 255) chunkSums[b] = lds[255];
}

__global__ void k_scan2(const int* __restrict__ chunkSums, int* __restrict__ chunkOffs, int nc) {
    __shared__ int lds[128];
    int t = threadIdx.x;
    int v = (t < nc) ? chunkSums[t] : 0;
    lds[t] = v;
    __syncthreads();
    for (int off = 1; off < 128; off <<= 1) {
        int x = lds[t];
        int y = (t >= off) ? lds[t - off] : 0;
        __syncthreads();
        lds[t] = x + y;
        __syncthreads();
    }
    chunkOffs[t] = lds[t] - v;
}

__global__ void k_scan3(int* rowptr, const int* __restrict__ chunkOffs, int n, int e) {
    int i = blockIdx.x * blockDim.x + threadIdx.x;
    if (i < n) rowptr[i] += chunkOffs[i >> 10];
    if (i == 0) rowptr[n] = e;
}

// ---- CSR fill: eSrc ordered by destination ---------------------------------
__global__ void k_fill(const int* __restrict__ row, const int* __restrict__ col,
                       const int* __restrict__ rowptr, int* cursor, int* __restrict__ eSrc, int e) {
    int i = blockIdx.x * blockDim.x + threadIdx.x;
    if (i >= e) return;
    int c = col[i];
    int pos = atomicAdd(&cursor[c], 1);
    eSrc[rowptr[c] + pos] = row[i];
}

// ---- gather aggregation: out[i] = dinv[i]*(dinv[i]*in[i] + sum dinv[s]*in[s])
// one wave per node, CH = F/VEC lanes active (54 for both configs)
template <int F, int VEC>
__global__ void k_gather(const int* __restrict__ rowptr, const int* __restrict__ eSrc,
                         const float* __restrict__ dinv, const float* __restrict__ in,
                         float* __restrict__ out, int n) {
    constexpr int CH = F / VEC;
    int wave = threadIdx.x >> 6;
    int lane = threadIdx.x & 63;
    int node = blockIdx.x * (blockDim.x >> 6) + wave;
    if (node >= n || lane >= CH) return;
    float di = dinv[node];
    const float* selfp = in + (long long)node * F + lane * VEC;
    float acc[VEC];
#pragma unroll
    for (int j = 0; j < VEC; j++) acc[j] = di * selfp[j];
    int rs = rowptr[node], re = rowptr[node + 1];
    for (int e = rs; e < re; e++) {
        int s = eSrc[e];
        float ds = dinv[s];
        const float* sp = in + (long long)s * F + lane * VEC;
#pragma unroll
        for (int j = 0; j < VEC; j++) acc[j] += ds * sp[j];
    }
    float* op = out + (long long)node * F + lane * VEC;
#pragma unroll
    for (int j = 0; j < VEC; j++) op[j] = di * acc[j];
}

// ---- node GEMM: out[n,FOUT] = act(in[n,K] @ W[K,FOUT] + bias) --------------
template <int K, int FOUT, int VEC, bool RELU>
__global__ void k_gemm(const float* __restrict__ in, const float* __restrict__ W,
                       const float* __restrict__ bias, float* __restrict__ out, int n) {
    constexpr int CH = FOUT / VEC;
    int idx = blockIdx.x * blockDim.x + threadIdx.x;
    if (idx >= n * CH) return;
    int node = idx / CH;
    int c = idx - node * CH;
    const float* inrow = in + (long long)node * K;
    const float* wp = W + c * VEC;
    float acc[VEC];
#pragma unroll
    for (int j = 0; j < VEC; j++) acc[j] = 0.f;
    for (int k = 0; k < K; k++) {
        float a = inrow[k];
#pragma unroll
        for (int j = 0; j < VEC; j++) acc[j] += a * wp[k * FOUT + j];
    }
    float* op = out + (long long)node * FOUT + c * VEC;
#pragma unroll
    for (int j = 0; j < VEC; j++) {
        float o = acc[j] + bias[c * VEC + j];
        if (RELU) o = fmaxf(o, 0.f);
        op[j] = o;
    }
}

// ---- per-graph boundaries (batch sorted ascending) -------------------------
__global__ void k_init_start(int* start, int n, int g) {
    int i = blockIdx.x * blockDim.x + threadIdx.x;
    if (i <= g) start[i] = n;
}
__global__ void k_find_start(const int* __restrict__ batch, int* start, int n) {
    int i = blockIdx.x * blockDim.x + threadIdx.x;
    if (i >= n) return;
    int b = batch[i];
    int bp = (i == 0) ? -1 : batch[i - 1];
    for (int g = bp + 1; g <= b; g++) start[g] = i;
}

// ---- mean pool --------------------------------------------------------------
template <int F>
__global__ void k_pool(const float* __restrict__ h, const int* __restrict__ start,
                       float* __restrict__ pooled) {
    int g = blockIdx.x;
    int f = threadIdx.x;
    if (f >= F) return;
    int s = start[g], e = start[g + 1];
    float acc = 0.f;
    for (int nd = s; nd < e; nd++) acc += h[(long long)nd * F + f];
    float cnt = (float)(e - s);
    pooled[g * F + f] = acc / fmaxf(cnt, 1.0f);
}

// ---- FC layers -------------------------------------------------------------
__global__ void k_fc1(const float* __restrict__ P, const float* __restrict__ W,
                      const float* __restrict__ bias, float* __restrict__ out) {
    int row = blockIdx.x >> 2;
    int o = (blockIdx.x & 3) * 256 + threadIdx.x;
    __shared__ float prow[216];
    if (threadIdx.x < 216) prow[threadIdx.x] = P[row * 216 + threadIdx.x];
    __syncthreads();
    float acc = bias[o];
    for (int k = 0; k < 216; k++) acc += prow[k] * W[k * 1024 + o];
    out[row * 1024 + o] = fmaxf(acc, 0.f);
}
__global__ void k_fc2(const float* __restrict__ G, const float* __restrict__ W,
                      const float* __restrict__ bias, float* __restrict__ out) {
    int row = blockIdx.x;
    int o = threadIdx.x;  // 128
    __shared__ float grow[1024];
    for (int k = threadIdx.x; k < 1024; k += 128) grow[k] = G[row * 1024 + k];
    __syncthreads();
    float acc = bias[o];
    for (int k = 0; k < 1024; k++) acc += grow[k] * W[k * 128 + o];
    out[row * 128 + o] = acc;
}

// ---------------------------------------------------------------------------
extern "C" void kernel_launch(void* const* d_in, const int* in_sizes, int n_in,
                              void* d_out, int out_size, void* d_ws, size_t ws_size,
                              hipStream_t stream) {
    const float* x     = (const float*)d_in[0];
    const int*   ei    = (const int*)d_in[1];
    const int*   batch = (const int*)d_in[2];
    const float* W1  = (const float*)d_in[3];
    const float* b1  = (const float*)d_in[4];
    const float* W2  = (const float*)d_in[5];
    const float* b2  = (const float*)d_in[6];
    const float* W3  = (const float*)d_in[7];
    const float* b3  = (const float*)d_in[8];
    const float* Wf1 = (const float*)d_in[9];
    const float* bf1 = (const float*)d_in[10];
    const float* Wf2 = (const float*)d_in[11];
    const float* bf2 = (const float*)d_in[12];
    float* out = (float*)d_out;

    const int N = in_sizes[0] / 54;   // 100000
    const int E = in_sizes[1] / 2;    // 1600000
    const int G = 256;
    const int* row = ei;
    const int* col = ei + E;
    const int NCHUNK = cdiv(N, 1024); // 98

    // workspace carve-up (256B aligned)
    char* ws = (char*)d_ws;
    size_t off = 0;
    auto carve = [&](size_t bytes) {
        void* p = ws + off;
        off += (bytes + 255) & ~(size_t)255;
        return p;
    };
    int*   counts    = (int*)carve((size_t)2 * N * 4);  // counts + cursor, zeroed together
    int*   cursor    = counts + N;
    int*   rowptr    = (int*)carve((size_t)(N + 1) * 4);
    int*   chunkSums = (int*)carve(128 * 4);
    int*   chunkOffs = (int*)carve(128 * 4);
    int*   eSrc      = (int*)carve((size_t)E * 4);
    float* dinv      = (float*)carve((size_t)N * 4);
    float* bufA      = (float*)carve((size_t)N * 108 * 4);  // aggregation outputs (max F=108)
    float* bufB      = (float*)carve((size_t)N * 216 * 4);  // gemm outputs (max F=216)
    float* pooled    = (float*)carve((size_t)G * 216 * 4);
    float* gbuf      = (float*)carve((size_t)G * 1024 * 4);
    int*   start     = (int*)carve((size_t)(G + 1) * 4);

    const int T = 256;

    // ---- CSR build + norms ----
    k_zero_int<<<cdiv(2 * N, T), T, 0, stream>>>(counts, 2 * N);
    k_count<<<cdiv(E, T), T, 0, stream>>>(col, counts, E);
    k_scan1<<<NCHUNK, 256, 0, stream>>>(counts, rowptr, chunkSums, N);
    k_scan2<<<1, 128, 0, stream>>>(chunkSums, chunkOffs, NCHUNK);
    k_scan3<<<cdiv(N, T), T, 0, stream>>>(rowptr, chunkOffs, N, E);
    k_dinv<<<cdiv(N, T), T, 0, stream>>>(counts, dinv, N);
    k_fill<<<cdiv(E, T), T, 0, stream>>>(row, col, rowptr, cursor, eSrc, E);

    // ---- graph boundaries ----
    k_init_start<<<cdiv(G + 1, T), T, 0, stream>>>(start, N, G);
    k_find_start<<<cdiv(N, T), T, 0, stream>>>(batch, start, N);

    // ---- layer 1: a1 = A_hat x ; h1 = relu(a1@W1 + b1) ----
    k_gather<54, 1><<<cdiv(N, 4), 256, 0, stream>>>(rowptr, eSrc, dinv, x, bufA, N);
    k_gemm<54, 54, 2, true><<<cdiv(N * 27, T), T, 0, stream>>>(bufA, W1, b1, bufB, N);

    // ---- layer 2: a2 = A_hat h1 ; h2 = relu(a2@W2 + b2) ----
    k_gather<54, 1><<<cdiv(N, 4), 256, 0, stream>>>(rowptr, eSrc, dinv, bufB, bufA, N);
    k_gemm<54, 108, 4, true><<<cdiv(N * 27, T), T, 0, stream>>>(bufA, W2, b2, bufB, N);

    // ---- layer 3: a3 = A_hat h2 ; h3 = relu(a3@W3 + b3) ----
    k_gather<108, 2><<<cdiv(N, 4), 256, 0, stream>>>(rowptr, eSrc, dinv, bufB, bufA, N);
    k_gemm<108, 216, 4, true><<<cdiv(N * 54, T), T, 0, stream>>>(bufA, W3, b3, bufB, N);

    // ---- mean pool + FC head ----
    k_pool<216><<<G, T, 0, stream>>>(bufB, start, pooled);
    k_fc1<<<G * 4, T, 0, stream>>>(pooled, Wf1, bf1, gbuf);
    k_fc2<<<G, 128, 0, stream>>>(gbuf, Wf2, bf2, out);
}

// Round 3
// 1099.402 us; speedup vs baseline: 8.2193x; 1.2443x over previous
//
#include <hip/hip_runtime.h>

// ---------------------------------------------------------------------------
// ProteinGCNNet: 3x GCNConv + mean-pool + 2 FC layers, fp32.
// Round 3: node-tiled register-blocked node GEMM (NT=8 nodes/thread) to kill
// the per-wave W re-read that made layer GEMMs L2-BW bound.
// ---------------------------------------------------------------------------

static __host__ __device__ inline int cdiv(int a, int b) { return (a + b - 1) / b; }

// ---- zero int arrays -------------------------------------------------------
__global__ void k_zero_int(int* p, int n) {
    int i = blockIdx.x * blockDim.x + threadIdx.x;
    if (i < n) p[i] = 0;
}

// ---- in-degree histogram ---------------------------------------------------
__global__ void k_count(const int* __restrict__ col, int* counts, int e) {
    int i = blockIdx.x * blockDim.x + threadIdx.x;
    if (i < e) atomicAdd(&counts[col[i]], 1);
}

// ---- dinv[i] = rsqrt(counts[i] + 1) ----------------------------------------
__global__ void k_dinv(const int* __restrict__ counts, float* __restrict__ dinv, int n) {
    int i = blockIdx.x * blockDim.x + threadIdx.x;
    if (i < n) dinv[i] = rsqrtf((float)(counts[i] + 1));
}

// ---- prefix scan of counts -> rowptr (exclusive), chunked ------------------
__global__ void k_scan1(const int* __restrict__ counts, int* __restrict__ rowptr,
                        int* __restrict__ chunkSums, int n) {
    __shared__ int lds[256];
    int b = blockIdx.x, t = threadIdx.x;
    int base = b * 1024 + t * 4;
    int v[4], s = 0;
#pragma unroll
    for (int j = 0; j < 4; j++) {
        v[j] = (base + j < n) ? counts[base + j] : 0;
        s += v[j];
    }
    lds[t] = s;
    __syncthreads();
    for (int off = 1; off < 256; off <<= 1) {
        int x = lds[t];
        int y = (t >= off) ? lds[t - off] : 0;
        __syncthreads();
        lds[t] = x + y;
        __syncthreads();
    }
    int p = lds[t] - s;
#pragma unroll
    for (int j = 0; j < 4; j++) {
        if (base + j < n) rowptr[base + j] = p;
        p += v[j];
    }
    if (t == 255) chunkSums[b] = lds[255];
}

__global__ void k_scan2(const int* __restrict__ chunkSums, int* __restrict__ chunkOffs, int nc) {
    __shared__ int lds[128];
    int t = threadIdx.x;
    int v = (t < nc) ? chunkSums[t] : 0;
    lds[t] = v;
    __syncthreads();
    for (int off = 1; off < 128; off <<= 1) {
        int x = lds[t];
        int y = (t >= off) ? lds[t - off] : 0;
        __syncthreads();
        lds[t] = x + y;
        __syncthreads();
    }
    chunkOffs[t] = lds[t] - v;
}

__global__ void k_scan3(int* rowptr, const int* __restrict__ chunkOffs, int n, int e) {
    int i = blockIdx.x * blockDim.x + threadIdx.x;
    if (i < n) rowptr[i] += chunkOffs[i >> 10];
    if (i == 0) rowptr[n] = e;
}

// ---- CSR fill: eSrc ordered by destination ---------------------------------
__global__ void k_fill(const int* __restrict__ row, const int* __restrict__ col,
                       const int* __restrict__ rowptr, int* cursor, int* __restrict__ eSrc, int e) {
    int i = blockIdx.x * blockDim.x + threadIdx.x;
    if (i >= e) return;
    int c = col[i];
    int pos = atomicAdd(&cursor[c], 1);
    eSrc[rowptr[c] + pos] = row[i];
}

// ---- gather aggregation: out[i] = dinv[i]*(dinv[i]*in[i] + sum dinv[s]*in[s])
template <int F, int VEC>
__global__ void k_gather(const int* __restrict__ rowptr, const int* __restrict__ eSrc,
                         const float* __restrict__ dinv, const float* __restrict__ in,
                         float* __restrict__ out, int n) {
    constexpr int CH = F / VEC;
    int wave = threadIdx.x >> 6;
    int lane = threadIdx.x & 63;
    int node = blockIdx.x * (blockDim.x >> 6) + wave;
    if (node >= n || lane >= CH) return;
    float di = dinv[node];
    const float* selfp = in + (long long)node * F + lane * VEC;
    float acc[VEC];
#pragma unroll
    for (int j = 0; j < VEC; j++) acc[j] = di * selfp[j];
    int rs = rowptr[node], re = rowptr[node + 1];
    for (int e = rs; e < re; e++) {
        int s = eSrc[e];
        float ds = dinv[s];
        const float* sp = in + (long long)s * F + lane * VEC;
#pragma unroll
        for (int j = 0; j < VEC; j++) acc[j] += ds * sp[j];
    }
    float* op = out + (long long)node * F + lane * VEC;
#pragma unroll
    for (int j = 0; j < VEC; j++) op[j] = di * acc[j];
}

// ---- node GEMM, node-tiled: out[n,FOUT] = relu(in[n,K] @ W[K,FOUT] + bias) -
// Each thread: NT nodes x VEC output channels (NT*VEC accumulators).
// W read once per NT nodes -> 8x less L2 W-traffic than 1-node version.
template <int K, int FOUT, int VEC, int NT, bool RELU>
__global__ void k_gemm(const float* __restrict__ in, const float* __restrict__ W,
                       const float* __restrict__ bias, float* __restrict__ out, int n) {
    constexpr int CH = FOUT / VEC;
    int tid = blockIdx.x * blockDim.x + threadIdx.x;
    int tile = tid / CH;
    int c = tid - tile * CH;
    int node0 = tile * NT;
    if (node0 >= n) return;
    int nt = (node0 + NT <= n) ? NT : (n - node0);

    const float* wp = W + c * VEC;
    const float* ip = in + (long long)node0 * K;

    float acc[NT][VEC];
#pragma unroll
    for (int i = 0; i < NT; i++)
#pragma unroll
        for (int j = 0; j < VEC; j++) acc[i][j] = 0.f;

    if (nt == NT) {
        for (int k = 0; k < K; k++) {
            float wv[VEC];
#pragma unroll
            for (int j = 0; j < VEC; j++) wv[j] = wp[k * FOUT + j];
#pragma unroll
            for (int i = 0; i < NT; i++) {
                float a = ip[i * K + k];
#pragma unroll
                for (int j = 0; j < VEC; j++) acc[i][j] += a * wv[j];
            }
        }
    } else {
        for (int k = 0; k < K; k++) {
            float wv[VEC];
#pragma unroll
            for (int j = 0; j < VEC; j++) wv[j] = wp[k * FOUT + j];
            for (int i = 0; i < nt; i++) {
                float a = ip[i * K + k];
#pragma unroll
                for (int j = 0; j < VEC; j++) acc[i][j] += a * wv[j];
            }
        }
    }

    float bv[VEC];
#pragma unroll
    for (int j = 0; j < VEC; j++) bv[j] = bias[c * VEC + j];

    for (int i = 0; i < nt; i++) {
        float* op = out + (long long)(node0 + i) * FOUT + c * VEC;
#pragma unroll
        for (int j = 0; j < VEC; j++) {
            float o = acc[i][j] + bv[j];
            if (RELU) o = fmaxf(o, 0.f);
            op[j] = o;
        }
    }
}

// ---- per-graph boundaries (batch sorted ascending) -------------------------
__global__ void k_init_start(int* start, int n, int g) {
    int i = blockIdx.x * blockDim.x + threadIdx.x;
    if (i <= g) start[i] = n;
}
__global__ void k_find_start(const int* __restrict__ batch, int* start, int n) {
    int i = blockIdx.x * blockDim.x + threadIdx.x;
    if (i >= n) return;
    int b = batch[i];
    int bp = (i == 0) ? -1 : batch[i - 1];
    for (int g = bp + 1; g <= b; g++) start[g] = i;
}

// ---- mean pool --------------------------------------------------------------
template <int F>
__global__ void k_pool(const float* __restrict__ h, const int* __restrict__ start,
                       float* __restrict__ pooled) {
    int g = blockIdx.x;
    int f = threadIdx.x;
    if (f >= F) return;
    int s = start[g], e = start[g + 1];
    float acc = 0.f;
    for (int nd = s; nd < e; nd++) acc += h[(long long)nd * F + f];
    float cnt = (float)(e - s);
    pooled[g * F + f] = acc / fmaxf(cnt, 1.0f);
}

// ---- FC layers -------------------------------------------------------------
__global__ void k_fc1(const float* __restrict__ P, const float* __restrict__ W,
                      const float* __restrict__ bias, float* __restrict__ out) {
    int row = blockIdx.x >> 2;
    int o = (blockIdx.x & 3) * 256 + threadIdx.x;
    __shared__ float prow[216];
    if (threadIdx.x < 216) prow[threadIdx.x] = P[row * 216 + threadIdx.x];
    __syncthreads();
    float acc = bias[o];
    for (int k = 0; k < 216; k++) acc += prow[k] * W[k * 1024 + o];
    out[row * 1024 + o] = fmaxf(acc, 0.f);
}
__global__ void k_fc2(const float* __restrict__ G, const float* __restrict__ W,
                      const float* __restrict__ bias, float* __restrict__ out) {
    int row = blockIdx.x;
    int o = threadIdx.x;  // 128
    __shared__ float grow[1024];
    for (int k = threadIdx.x; k < 1024; k += 128) grow[k] = G[row * 1024 + k];
    __syncthreads();
    float acc = bias[o];
    for (int k = 0; k < 1024; k++) acc += grow[k] * W[k * 128 + o];
    out[row * 128 + o] = acc;
}

// ---------------------------------------------------------------------------
extern "C" void kernel_launch(void* const* d_in, const int* in_sizes, int n_in,
                              void* d_out, int out_size, void* d_ws, size_t ws_size,
                              hipStream_t stream) {
    const float* x     = (const float*)d_in[0];
    const int*   ei    = (const int*)d_in[1];
    const int*   batch = (const int*)d_in[2];
    const float* W1  = (const float*)d_in[3];
    const float* b1  = (const float*)d_in[4];
    const float* W2  = (const float*)d_in[5];
    const float* b2  = (const float*)d_in[6];
    const float* W3  = (const float*)d_in[7];
    const float* b3  = (const float*)d_in[8];
    const float* Wf1 = (const float*)d_in[9];
    const float* bf1 = (const float*)d_in[10];
    const float* Wf2 = (const float*)d_in[11];
    const float* bf2 = (const float*)d_in[12];
    float* out = (float*)d_out;

    const int N = in_sizes[0] / 54;   // 100000
    const int E = in_sizes[1] / 2;    // 1600000
    const int G = 256;
    const int* row = ei;
    const int* col = ei + E;
    const int NCHUNK = cdiv(N, 1024);

    // workspace carve-up (256B aligned)
    char* ws = (char*)d_ws;
    size_t off = 0;
    auto carve = [&](size_t bytes) {
        void* p = ws + off;
        off += (bytes + 255) & ~(size_t)255;
        return p;
    };
    int*   counts    = (int*)carve((size_t)2 * N * 4);
    int*   cursor    = counts + N;
    int*   rowptr    = (int*)carve((size_t)(N + 1) * 4);
    int*   chunkSums = (int*)carve(128 * 4);
    int*   chunkOffs = (int*)carve(128 * 4);
    int*   eSrc      = (int*)carve((size_t)E * 4);
    float* dinv      = (float*)carve((size_t)N * 4);
    float* bufA      = (float*)carve((size_t)N * 108 * 4);
    float* bufB      = (float*)carve((size_t)N * 216 * 4);
    float* pooled    = (float*)carve((size_t)G * 216 * 4);
    float* gbuf      = (float*)carve((size_t)G * 1024 * 4);
    int*   start     = (int*)carve((size_t)(G + 1) * 4);

    const int T = 256;
    const int NT = 8;

    // ---- CSR build + norms ----
    k_zero_int<<<cdiv(2 * N, T), T, 0, stream>>>(counts, 2 * N);
    k_count<<<cdiv(E, T), T, 0, stream>>>(col, counts, E);
    k_scan1<<<NCHUNK, 256, 0, stream>>>(counts, rowptr, chunkSums, N);
    k_scan2<<<1, 128, 0, stream>>>(chunkSums, chunkOffs, NCHUNK);
    k_scan3<<<cdiv(N, T), T, 0, stream>>>(rowptr, chunkOffs, N, E);
    k_dinv<<<cdiv(N, T), T, 0, stream>>>(counts, dinv, N);
    k_fill<<<cdiv(E, T), T, 0, stream>>>(row, col, rowptr, cursor, eSrc, E);

    // ---- graph boundaries ----
    k_init_start<<<cdiv(G + 1, T), T, 0, stream>>>(start, N, G);
    k_find_start<<<cdiv(N, T), T, 0, stream>>>(batch, start, N);

    const int tiles = cdiv(N, NT);

    // ---- layer 1: a1 = A_hat x ; h1 = relu(a1@W1 + b1) ----
    k_gather<54, 1><<<cdiv(N, 4), 256, 0, stream>>>(rowptr, eSrc, dinv, x, bufA, N);
    k_gemm<54, 54, 2, NT, true><<<cdiv(tiles * 27, T), T, 0, stream>>>(bufA, W1, b1, bufB, N);

    // ---- layer 2: a2 = A_hat h1 ; h2 = relu(a2@W2 + b2) ----
    k_gather<54, 1><<<cdiv(N, 4), 256, 0, stream>>>(rowptr, eSrc, dinv, bufB, bufA, N);
    k_gemm<54, 108, 4, NT, true><<<cdiv(tiles * 27, T), T, 0, stream>>>(bufA, W2, b2, bufB, N);

    // ---- layer 3: a3 = A_hat h2 ; h3 = relu(a3@W3 + b3) ----
    k_gather<108, 2><<<cdiv(N, 4), 256, 0, stream>>>(rowptr, eSrc, dinv, bufB, bufA, N);
    k_gemm<108, 216, 4, NT, true><<<cdiv(tiles * 54, T), T, 0, stream>>>(bufA, W3, b3, bufB, N);

    // ---- mean pool + FC head ----
    k_pool<216><<<G, T, 0, stream>>>(bufB, start, pooled);
    k_fc1<<<G * 4, T, 0, stream>>>(pooled, Wf1, bf1, gbuf);
    k_fc2<<<G, 128, 0, stream>>>(gbuf, Wf2, bf2, out);
}

// Round 4
// 839.323 us; speedup vs baseline: 10.7662x; 1.3099x over previous
//
#include <hip/hip_runtime.h>

// ---------------------------------------------------------------------------
// ProteinGCNNet: 3x GCNConv + mean-pool + 2 FC layers, fp32.
// Round 4: (1) k-vectorized GEMM (float4 a/W loads, 3x fewer VMEM issues),
//          (2) gather edge-loop unroll x4 (4x memory-level parallelism),
//          (3) segmented parallel pool with atomic merge.
// ---------------------------------------------------------------------------

static __host__ __device__ inline int cdiv(int a, int b) { return (a + b - 1) / b; }

template <int V>
__device__ __forceinline__ void vload(float* d, const float* s) {
    if constexpr (V == 1) { d[0] = s[0]; }
    else if constexpr (V == 2) { float2 t = *reinterpret_cast<const float2*>(s); d[0] = t.x; d[1] = t.y; }
    else { float4 t = *reinterpret_cast<const float4*>(s); d[0] = t.x; d[1] = t.y; d[2] = t.z; d[3] = t.w; }
}
template <int V>
__device__ __forceinline__ void vstore(float* dst, const float* s) {
    if constexpr (V == 1) { dst[0] = s[0]; }
    else if constexpr (V == 2) { *reinterpret_cast<float2*>(dst) = make_float2(s[0], s[1]); }
    else { *reinterpret_cast<float4*>(dst) = make_float4(s[0], s[1], s[2], s[3]); }
}

// ---- zero ------------------------------------------------------------------
__global__ void k_zero_int(int* p, int n) {
    int i = blockIdx.x * blockDim.x + threadIdx.x;
    if (i < n) p[i] = 0;
}
__global__ void k_zero_f(float* p, int n) {
    int i = blockIdx.x * blockDim.x + threadIdx.x;
    if (i < n) p[i] = 0.f;
}

// ---- in-degree histogram ---------------------------------------------------
__global__ void k_count(const int* __restrict__ col, int* counts, int e) {
    int i = blockIdx.x * blockDim.x + threadIdx.x;
    if (i < e) atomicAdd(&counts[col[i]], 1);
}

// ---- dinv[i] = rsqrt(counts[i] + 1) ----------------------------------------
__global__ void k_dinv(const int* __restrict__ counts, float* __restrict__ dinv, int n) {
    int i = blockIdx.x * blockDim.x + threadIdx.x;
    if (i < n) dinv[i] = rsqrtf((float)(counts[i] + 1));
}

// ---- prefix scan of counts -> rowptr (exclusive), chunked ------------------
__global__ void k_scan1(const int* __restrict__ counts, int* __restrict__ rowptr,
                        int* __restrict__ chunkSums, int n) {
    __shared__ int lds[256];
    int b = blockIdx.x, t = threadIdx.x;
    int base = b * 1024 + t * 4;
    int v[4], s = 0;
#pragma unroll
    for (int j = 0; j < 4; j++) {
        v[j] = (base + j < n) ? counts[base + j] : 0;
        s += v[j];
    }
    lds[t] = s;
    __syncthreads();
    for (int off = 1; off < 256; off <<= 1) {
        int x = lds[t];
        int y = (t >= off) ? lds[t - off] : 0;
        __syncthreads();
        lds[t] = x + y;
        __syncthreads();
    }
    int p = lds[t] - s;
#pragma unroll
    for (int j = 0; j < 4; j++) {
        if (base + j < n) rowptr[base + j] = p;
        p += v[j];
    }
    if (t == 255) chunkSums[b] = lds[255];
}

__global__ void k_scan2(const int* __restrict__ chunkSums, int* __restrict__ chunkOffs, int nc) {
    __shared__ int lds[128];
    int t = threadIdx.x;
    int v = (t < nc) ? chunkSums[t] : 0;
    lds[t] = v;
    __syncthreads();
    for (int off = 1; off < 128; off <<= 1) {
        int x = lds[t];
        int y = (t >= off) ? lds[t - off] : 0;
        __syncthreads();
        lds[t] = x + y;
        __syncthreads();
    }
    chunkOffs[t] = lds[t] - v;
}

__global__ void k_scan3(int* rowptr, const int* __restrict__ chunkOffs, int n, int e) {
    int i = blockIdx.x * blockDim.x + threadIdx.x;
    if (i < n) rowptr[i] += chunkOffs[i >> 10];
    if (i == 0) rowptr[n] = e;
}

// ---- CSR fill: eSrc ordered by destination ---------------------------------
__global__ void k_fill(const int* __restrict__ row, const int* __restrict__ col,
                       const int* __restrict__ rowptr, int* cursor, int* __restrict__ eSrc, int e) {
    int i = blockIdx.x * blockDim.x + threadIdx.x;
    if (i >= e) return;
    int c = col[i];
    int pos = atomicAdd(&cursor[c], 1);
    eSrc[rowptr[c] + pos] = row[i];
}

// ---- gather aggregation, edge-unroll x4 ------------------------------------
// out[i] = dinv[i]*(dinv[i]*in[i] + sum_s dinv[s]*in[s])
template <int F, int VEC>
__global__ __launch_bounds__(256) void k_gather(
        const int* __restrict__ rowptr, const int* __restrict__ eSrc,
        const float* __restrict__ dinv, const float* __restrict__ in,
        float* __restrict__ out, int n) {
    constexpr int CH = F / VEC;
    int wave = threadIdx.x >> 6;
    int lane = threadIdx.x & 63;
    int node = blockIdx.x * (blockDim.x >> 6) + wave;
    if (node >= n || lane >= CH) return;
    float di = dinv[node];
    float acc[VEC];
    vload<VEC>(acc, in + (long long)node * F + lane * VEC);
#pragma unroll
    for (int j = 0; j < VEC; j++) acc[j] *= di;

    int rs = rowptr[node], re = rowptr[node + 1];
    int e = rs;
    for (; e + 4 <= re; e += 4) {
        int s0 = eSrc[e + 0], s1 = eSrc[e + 1], s2 = eSrc[e + 2], s3 = eSrc[e + 3];
        float d0 = dinv[s0], d1 = dinv[s1], d2 = dinv[s2], d3 = dinv[s3];
        float v0[VEC], v1[VEC], v2[VEC], v3[VEC];
        vload<VEC>(v0, in + (long long)s0 * F + lane * VEC);
        vload<VEC>(v1, in + (long long)s1 * F + lane * VEC);
        vload<VEC>(v2, in + (long long)s2 * F + lane * VEC);
        vload<VEC>(v3, in + (long long)s3 * F + lane * VEC);
#pragma unroll
        for (int j = 0; j < VEC; j++)
            acc[j] += d0 * v0[j] + d1 * v1[j] + d2 * v2[j] + d3 * v3[j];
    }
    for (; e < re; e++) {
        int s = eSrc[e];
        float ds = dinv[s];
        float v[VEC];
        vload<VEC>(v, in + (long long)s * F + lane * VEC);
#pragma unroll
        for (int j = 0; j < VEC; j++) acc[j] += ds * v[j];
    }
#pragma unroll
    for (int j = 0; j < VEC; j++) acc[j] *= di;
    vstore<VEC>(out + (long long)node * F + lane * VEC, acc);
}

// ---- node GEMM, node-tiled + k-vectorized ----------------------------------
// out[n,FOUT] = relu(in[n,K] @ W[K,FOUT] + bias); NT nodes x VEC channels per
// thread; K-loop in steps of KS with vector a/W loads.
template <int K, int FOUT, int VEC, int NT, int KS, bool RELU>
__global__ __launch_bounds__(256) void k_gemm(
        const float* __restrict__ in, const float* __restrict__ W,
        const float* __restrict__ bias, float* __restrict__ out, int n) {
    constexpr int CH = FOUT / VEC;
    int tid = blockIdx.x * blockDim.x + threadIdx.x;
    int tile = tid / CH;
    int c = tid - tile * CH;
    int node0 = tile * NT;
    if (node0 >= n) return;

    const float* wp = W + c * VEC;
    const float* ip = in + (long long)node0 * K;

    float acc[NT][VEC];
#pragma unroll
    for (int i = 0; i < NT; i++)
#pragma unroll
        for (int j = 0; j < VEC; j++) acc[i][j] = 0.f;

    if (node0 + NT <= n) {
        for (int k0 = 0; k0 < K; k0 += KS) {
            float w[KS][VEC];
#pragma unroll
            for (int kk = 0; kk < KS; kk++) vload<VEC>(w[kk], wp + (k0 + kk) * FOUT);
#pragma unroll
            for (int i = 0; i < NT; i++) {
                float a[KS];
                vload<KS>(a, ip + i * K + k0);
#pragma unroll
                for (int kk = 0; kk < KS; kk++)
#pragma unroll
                    for (int j = 0; j < VEC; j++) acc[i][j] += a[kk] * w[kk][j];
            }
        }
        float bv[VEC];
#pragma unroll
        for (int j = 0; j < VEC; j++) bv[j] = bias[c * VEC + j];
#pragma unroll
        for (int i = 0; i < NT; i++) {
            float o[VEC];
#pragma unroll
            for (int j = 0; j < VEC; j++) {
                o[j] = acc[i][j] + bv[j];
                if (RELU) o[j] = fmaxf(o[j], 0.f);
            }
            vstore<VEC>(out + (long long)(node0 + i) * FOUT + c * VEC, o);
        }
    } else {
        int nt = n - node0;
        for (int k = 0; k < K; k++) {
            float w[VEC];
            vload<VEC>(w, wp + k * FOUT);
            for (int i = 0; i < nt; i++) {
                float a = ip[i * K + k];
#pragma unroll
                for (int j = 0; j < VEC; j++) acc[i][j] += a * w[j];
            }
        }
        for (int i = 0; i < nt; i++) {
            float o[VEC];
#pragma unroll
            for (int j = 0; j < VEC; j++) {
                o[j] = acc[i][j] + bias[c * VEC + j];
                if (RELU) o[j] = fmaxf(o[j], 0.f);
            }
            vstore<VEC>(out + (long long)(node0 + i) * FOUT + c * VEC, o);
        }
    }
}

// ---- per-graph boundaries (batch sorted ascending) -------------------------
__global__ void k_init_start(int* start, int n, int g) {
    int i = blockIdx.x * blockDim.x + threadIdx.x;
    if (i <= g) start[i] = n;
}
__global__ void k_find_start(const int* __restrict__ batch, int* start, int n) {
    int i = blockIdx.x * blockDim.x + threadIdx.x;
    if (i >= n) return;
    int b = batch[i];
    int bp = (i == 0) ? -1 : batch[i - 1];
    for (int g = bp + 1; g <= b; g++) start[g] = i;
}

// ---- segmented mean-pool: psum[g,f] += sum over node segment ---------------
template <int F, int NSEG>
__global__ void k_pool(const float* __restrict__ h, const int* __restrict__ start,
                       float* __restrict__ psum) {
    int g = blockIdx.x / NSEG;
    int seg = blockIdx.x - g * NSEG;
    int f = threadIdx.x;
    if (f >= F) return;
    int s = start[g], e = start[g + 1];
    int len = e - s;
    int chunk = (len + NSEG - 1) / NSEG;
    int cs = s + seg * chunk;
    int ce = cs + chunk < e ? cs + chunk : e;
    if (cs >= ce) return;
    float acc = 0.f;
    for (int nd = cs; nd < ce; nd++) acc += h[(long long)nd * F + f];
    atomicAdd(&psum[g * F + f], acc);
}

// ---- FC layers (fc1 folds the mean divide) ---------------------------------
__global__ void k_fc1(const float* __restrict__ P, const int* __restrict__ start,
                      const float* __restrict__ W, const float* __restrict__ bias,
                      float* __restrict__ out) {
    int row = blockIdx.x >> 2;
    int o = (blockIdx.x & 3) * 256 + threadIdx.x;
    int cnt = start[row + 1] - start[row];
    float scale = 1.0f / fmaxf((float)cnt, 1.0f);
    __shared__ float prow[216];
    if (threadIdx.x < 216) prow[threadIdx.x] = P[row * 216 + threadIdx.x] * scale;
    __syncthreads();
    float acc = bias[o];
    for (int k = 0; k < 216; k++) acc += prow[k] * W[k * 1024 + o];
    out[row * 1024 + o] = fmaxf(acc, 0.f);
}
__global__ void k_fc2(const float* __restrict__ G, const float* __restrict__ W,
                      const float* __restrict__ bias, float* __restrict__ out) {
    int row = blockIdx.x;
    int o = threadIdx.x;  // 128
    __shared__ float grow[1024];
    for (int k = threadIdx.x; k < 1024; k += 128) grow[k] = G[row * 1024 + k];
    __syncthreads();
    float acc = bias[o];
    for (int k = 0; k < 1024; k++) acc += grow[k] * W[k * 128 + o];
    out[row * 128 + o] = acc;
}

// ---------------------------------------------------------------------------
extern "C" void kernel_launch(void* const* d_in, const int* in_sizes, int n_in,
                              void* d_out, int out_size, void* d_ws, size_t ws_size,
                              hipStream_t stream) {
    const float* x     = (const float*)d_in[0];
    const int*   ei    = (const int*)d_in[1];
    const int*   batch = (const int*)d_in[2];
    const float* W1  = (const float*)d_in[3];
    const float* b1  = (const float*)d_in[4];
    const float* W2  = (const float*)d_in[5];
    const float* b2  = (const float*)d_in[6];
    const float* W3  = (const float*)d_in[7];
    const float* b3  = (const float*)d_in[8];
    const float* Wf1 = (const float*)d_in[9];
    const float* bf1 = (const float*)d_in[10];
    const float* Wf2 = (const float*)d_in[11];
    const float* bf2 = (const float*)d_in[12];
    float* out = (float*)d_out;

    const int N = in_sizes[0] / 54;   // 100000
    const int E = in_sizes[1] / 2;    // 1600000
    const int G = 256;
    const int* row = ei;
    const int* col = ei + E;
    const int NCHUNK = cdiv(N, 1024);

    // workspace carve-up (256B aligned)
    char* ws = (char*)d_ws;
    size_t off = 0;
    auto carve = [&](size_t bytes) {
        void* p = ws + off;
        off += (bytes + 255) & ~(size_t)255;
        return p;
    };
    int*   counts    = (int*)carve((size_t)2 * N * 4);
    int*   cursor    = counts + N;
    int*   rowptr    = (int*)carve((size_t)(N + 1) * 4);
    int*   chunkSums = (int*)carve(128 * 4);
    int*   chunkOffs = (int*)carve(128 * 4);
    int*   eSrc      = (int*)carve((size_t)E * 4);
    float* dinv      = (float*)carve((size_t)N * 4);
    float* bufA      = (float*)carve((size_t)N * 108 * 4);
    float* bufB      = (float*)carve((size_t)N * 216 * 4);
    float* psum      = (float*)carve((size_t)G * 216 * 4);
    float* gbuf      = (float*)carve((size_t)G * 1024 * 4);
    int*   start     = (int*)carve((size_t)(G + 1) * 4);

    const int T = 256;
    const int NT = 8;

    // ---- CSR build + norms + zeroing ----
    k_zero_int<<<cdiv(2 * N, T), T, 0, stream>>>(counts, 2 * N);
    k_zero_f<<<cdiv(G * 216, T), T, 0, stream>>>(psum, G * 216);
    k_count<<<cdiv(E, T), T, 0, stream>>>(col, counts, E);
    k_scan1<<<NCHUNK, 256, 0, stream>>>(counts, rowptr, chunkSums, N);
    k_scan2<<<1, 128, 0, stream>>>(chunkSums, chunkOffs, NCHUNK);
    k_scan3<<<cdiv(N, T), T, 0, stream>>>(rowptr, chunkOffs, N, E);
    k_dinv<<<cdiv(N, T), T, 0, stream>>>(counts, dinv, N);
    k_fill<<<cdiv(E, T), T, 0, stream>>>(row, col, rowptr, cursor, eSrc, E);

    // ---- graph boundaries ----
    k_init_start<<<cdiv(G + 1, T), T, 0, stream>>>(start, N, G);
    k_find_start<<<cdiv(N, T), T, 0, stream>>>(batch, start, N);

    const int tiles = cdiv(N, NT);

    // ---- layer 1: a1 = A_hat x ; h1 = relu(a1@W1 + b1) ----
    k_gather<54, 1><<<cdiv(N, 4), 256, 0, stream>>>(rowptr, eSrc, dinv, x, bufA, N);
    k_gemm<54, 54, 2, NT, 2, true><<<cdiv(tiles * 27, T), T, 0, stream>>>(bufA, W1, b1, bufB, N);

    // ---- layer 2: a2 = A_hat h1 ; h2 = relu(a2@W2 + b2) ----
    k_gather<54, 1><<<cdiv(N, 4), 256, 0, stream>>>(rowptr, eSrc, dinv, bufB, bufA, N);
    k_gemm<54, 108, 4, NT, 2, true><<<cdiv(tiles * 27, T), T, 0, stream>>>(bufA, W2, b2, bufB, N);

    // ---- layer 3: a3 = A_hat h2 ; h3 = relu(a3@W3 + b3) ----
    k_gather<108, 2><<<cdiv(N, 4), 256, 0, stream>>>(rowptr, eSrc, dinv, bufB, bufA, N);
    k_gemm<108, 216, 4, NT, 4, true><<<cdiv(tiles * 54, T), T, 0, stream>>>(bufA, W3, b3, bufB, N);

    // ---- mean pool (segmented) + FC head ----
    k_pool<216, 4><<<G * 4, T, 0, stream>>>(bufB, start, psum);
    k_fc1<<<G * 4, T, 0, stream>>>(psum, start, Wf1, bf1, gbuf);
    k_fc2<<<G, 128, 0, stream>>>(gbuf, Wf2, bf2, out);
}

// Round 5
// 730.391 us; speedup vs baseline: 12.3718x; 1.1491x over previous
//
#include <hip/hip_runtime.h>

// ---------------------------------------------------------------------------
// ProteinGCNNet: 3x GCNConv + mean-pool + 2 FC layers, fp32.
// Round 5: LDS-tiled node GEMM. Block = 72 nodes x all FOUT channels; a-tile
// staged transposed [k][node] in LDS (stride 80 -> b128 reads, ~conflict-free)
// kills the x54 activation re-read from L2 that bounded the GEMMs.
// ---------------------------------------------------------------------------

static __host__ __device__ inline int cdiv(int a, int b) { return (a + b - 1) / b; }

template <int V>
__device__ __forceinline__ void vload(float* d, const float* s) {
    if constexpr (V == 1) { d[0] = s[0]; }
    else if constexpr (V == 2) { float2 t = *reinterpret_cast<const float2*>(s); d[0] = t.x; d[1] = t.y; }
    else if constexpr (V == 4) { float4 t = *reinterpret_cast<const float4*>(s); d[0] = t.x; d[1] = t.y; d[2] = t.z; d[3] = t.w; }
    else { vload<4>(d, s); vload<4>(d + 4, s + 4); }
}
template <int V>
__device__ __forceinline__ void vstore(float* dst, const float* s) {
    if constexpr (V == 1) { dst[0] = s[0]; }
    else if constexpr (V == 2) { *reinterpret_cast<float2*>(dst) = make_float2(s[0], s[1]); }
    else if constexpr (V == 4) { *reinterpret_cast<float4*>(dst) = make_float4(s[0], s[1], s[2], s[3]); }
    else { vstore<4>(dst, s); vstore<4>(dst + 4, s + 4); }
}

// ---- zero ------------------------------------------------------------------
__global__ void k_zero_int(int* p, int n) {
    int i = blockIdx.x * blockDim.x + threadIdx.x;
    if (i < n) p[i] = 0;
}
__global__ void k_zero_f(float* p, int n) {
    int i = blockIdx.x * blockDim.x + threadIdx.x;
    if (i < n) p[i] = 0.f;
}

// ---- in-degree histogram ---------------------------------------------------
__global__ void k_count(const int* __restrict__ col, int* counts, int e) {
    int i = blockIdx.x * blockDim.x + threadIdx.x;
    if (i < e) atomicAdd(&counts[col[i]], 1);
}

// ---- dinv[i] = rsqrt(counts[i] + 1) ----------------------------------------
__global__ void k_dinv(const int* __restrict__ counts, float* __restrict__ dinv, int n) {
    int i = blockIdx.x * blockDim.x + threadIdx.x;
    if (i < n) dinv[i] = rsqrtf((float)(counts[i] + 1));
}

// ---- prefix scan of counts -> rowptr (exclusive), chunked ------------------
__global__ void k_scan1(const int* __restrict__ counts, int* __restrict__ rowptr,
                        int* __restrict__ chunkSums, int n) {
    __shared__ int lds[256];
    int b = blockIdx.x, t = threadIdx.x;
    int base = b * 1024 + t * 4;
    int v[4], s = 0;
#pragma unroll
    for (int j = 0; j < 4; j++) {
        v[j] = (base + j < n) ? counts[base + j] : 0;
        s += v[j];
    }
    lds[t] = s;
    __syncthreads();
    for (int off = 1; off < 256; off <<= 1) {
        int x = lds[t];
        int y = (t >= off) ? lds[t - off] : 0;
        __syncthreads();
        lds[t] = x + y;
        __syncthreads();
    }
    int p = lds[t] - s;
#pragma unroll
    for (int j = 0; j < 4; j++) {
        if (base + j < n) rowptr[base + j] = p;
        p += v[j];
    }
    if (t == 255) chunkSums[b] = lds[255];
}

__global__ void k_scan2(const int* __restrict__ chunkSums, int* __restrict__ chunkOffs, int nc) {
    __shared__ int lds[128];
    int t = threadIdx.x;
    int v = (t < nc) ? chunkSums[t] : 0;
    lds[t] = v;
    __syncthreads();
    for (int off = 1; off < 128; off <<= 1) {
        int x = lds[t];
        int y = (t >= off) ? lds[t - off] : 0;
        __syncthreads();
        lds[t] = x + y;
        __syncthreads();
    }
    chunkOffs[t] = lds[t] - v;
}

__global__ void k_scan3(int* rowptr, const int* __restrict__ chunkOffs, int n, int e) {
    int i = blockIdx.x * blockDim.x + threadIdx.x;
    if (i < n) rowptr[i] += chunkOffs[i >> 10];
    if (i == 0) rowptr[n] = e;
}

// ---- CSR fill: eSrc ordered by destination ---------------------------------
__global__ void k_fill(const int* __restrict__ row, const int* __restrict__ col,
                       const int* __restrict__ rowptr, int* cursor, int* __restrict__ eSrc, int e) {
    int i = blockIdx.x * blockDim.x + threadIdx.x;
    if (i >= e) return;
    int c = col[i];
    int pos = atomicAdd(&cursor[c], 1);
    eSrc[rowptr[c] + pos] = row[i];
}

// ---- gather aggregation, edge-unroll x4 ------------------------------------
// out[i] = dinv[i]*(dinv[i]*in[i] + sum_s dinv[s]*in[s])
template <int F, int VEC>
__global__ __launch_bounds__(256) void k_gather(
        const int* __restrict__ rowptr, const int* __restrict__ eSrc,
        const float* __restrict__ dinv, const float* __restrict__ in,
        float* __restrict__ out, int n) {
    constexpr int CH = F / VEC;
    int wave = threadIdx.x >> 6;
    int lane = threadIdx.x & 63;
    int node = blockIdx.x * (blockDim.x >> 6) + wave;
    if (node >= n || lane >= CH) return;
    float di = dinv[node];
    float acc[VEC];
    vload<VEC>(acc, in + (long long)node * F + lane * VEC);
#pragma unroll
    for (int j = 0; j < VEC; j++) acc[j] *= di;

    int rs = rowptr[node], re = rowptr[node + 1];
    int e = rs;
    for (; e + 4 <= re; e += 4) {
        int s0 = eSrc[e + 0], s1 = eSrc[e + 1], s2 = eSrc[e + 2], s3 = eSrc[e + 3];
        float d0 = dinv[s0], d1 = dinv[s1], d2 = dinv[s2], d3 = dinv[s3];
        float v0[VEC], v1[VEC], v2[VEC], v3[VEC];
        vload<VEC>(v0, in + (long long)s0 * F + lane * VEC);
        vload<VEC>(v1, in + (long long)s1 * F + lane * VEC);
        vload<VEC>(v2, in + (long long)s2 * F + lane * VEC);
        vload<VEC>(v3, in + (long long)s3 * F + lane * VEC);
#pragma unroll
        for (int j = 0; j < VEC; j++)
            acc[j] += d0 * v0[j] + d1 * v1[j] + d2 * v2[j] + d3 * v3[j];
    }
    for (; e < re; e++) {
        int s = eSrc[e];
        float ds = dinv[s];
        float v[VEC];
        vload<VEC>(v, in + (long long)s * F + lane * VEC);
#pragma unroll
        for (int j = 0; j < VEC; j++) acc[j] += ds * v[j];
    }
#pragma unroll
    for (int j = 0; j < VEC; j++) acc[j] *= di;
    vstore<VEC>(out + (long long)node * F + lane * VEC, acc);
}

// ---- LDS-tiled node GEMM ---------------------------------------------------
// out[n,FOUT] = relu(in[n,K] @ W[K,FOUT] + bias)
// Block: M=72 nodes x FOUT channels. a-tile staged TRANSPOSED in LDS:
// a_lds[k][node], row stride LROW=80 floats (b128-aligned, bank-spread).
// Thread (cg, strip): cg in [0,27) channel-group of VEC, strip in [0,9)
// node-strip of 8 nodes. Inner loop: per k, broadcast 8 nodes from LDS
// (2x ds_read_b128) + coalesced W row load + NT*VEC FMAs.
template <int K, int FOUT, int VEC, bool RELU>
__global__ __launch_bounds__(256) void k_gemm_lds(
        const float* __restrict__ in, const float* __restrict__ W,
        const float* __restrict__ bias, float* __restrict__ out, int n) {
    constexpr int M = 72, NT = 8, CG = FOUT / VEC;  // CG == 27
    constexpr int LROW = 80;                         // 72 + 8 pad
    constexpr int KV = (K % 4 == 0) ? 4 : 2;         // staging vector width
    constexpr int GPN = K / KV;                      // k-groups per node (27)
    constexpr int TOT = GPN * M;                     // 1944
    static_assert(CG == 27, "FOUT must be 27*VEC");

    __shared__ float a_lds[K * LROW];

    int t = threadIdx.x;
    int node0 = blockIdx.x * M;

    // ---- staging: global a[node][k] -> LDS a_lds[k][node] ----
    for (int it = 0; it < (TOT + 255) / 256; it++) {
        int f = t + it * 256;
        if (f < TOT) {
            int node = f / GPN;
            int kq = f - node * GPN;
            float v[KV] = {};
            if (node0 + node < n)
                vload<KV>(v, in + (long long)(node0 + node) * K + kq * KV);
#pragma unroll
            for (int j = 0; j < KV; j++)
                a_lds[(kq * KV + j) * LROW + node] = v[j];
        }
    }
    __syncthreads();

    if (t >= 243) return;
    int cg = t % 27;
    int strip = t / 27;

    float acc[NT][VEC];
#pragma unroll
    for (int i = 0; i < NT; i++)
#pragma unroll
        for (int j = 0; j < VEC; j++) acc[i][j] = 0.f;

    const float* wp = W + cg * VEC;
    for (int k = 0; k < K; k++) {
        float w[VEC];
        vload<VEC>(w, wp + k * FOUT);
        float av[NT];
        vload<NT>(av, &a_lds[k * LROW + strip * NT]);
#pragma unroll
        for (int i = 0; i < NT; i++)
#pragma unroll
            for (int j = 0; j < VEC; j++) acc[i][j] += av[i] * w[j];
    }

    float bv[VEC];
    vload<VEC>(bv, bias + cg * VEC);
#pragma unroll
    for (int i = 0; i < NT; i++) {
        int node = node0 + strip * NT + i;
        if (node >= n) break;
        float o[VEC];
#pragma unroll
        for (int j = 0; j < VEC; j++) {
            o[j] = acc[i][j] + bv[j];
            if (RELU) o[j] = fmaxf(o[j], 0.f);
        }
        vstore<VEC>(out + (long long)node * FOUT + cg * VEC, o);
    }
}

// ---- per-graph boundaries (batch sorted ascending) -------------------------
__global__ void k_init_start(int* start, int n, int g) {
    int i = blockIdx.x * blockDim.x + threadIdx.x;
    if (i <= g) start[i] = n;
}
__global__ void k_find_start(const int* __restrict__ batch, int* start, int n) {
    int i = blockIdx.x * blockDim.x + threadIdx.x;
    if (i >= n) return;
    int b = batch[i];
    int bp = (i == 0) ? -1 : batch[i - 1];
    for (int g = bp + 1; g <= b; g++) start[g] = i;
}

// ---- segmented mean-pool: psum[g,f] += sum over node segment ---------------
template <int F, int NSEG>
__global__ void k_pool(const float* __restrict__ h, const int* __restrict__ start,
                       float* __restrict__ psum) {
    int g = blockIdx.x / NSEG;
    int seg = blockIdx.x - g * NSEG;
    int f = threadIdx.x;
    if (f >= F) return;
    int s = start[g], e = start[g + 1];
    int len = e - s;
    int chunk = (len + NSEG - 1) / NSEG;
    int cs = s + seg * chunk;
    int ce = cs + chunk < e ? cs + chunk : e;
    if (cs >= ce) return;
    float acc = 0.f;
    for (int nd = cs; nd < ce; nd++) acc += h[(long long)nd * F + f];
    atomicAdd(&psum[g * F + f], acc);
}

// ---- FC layers (fc1 folds the mean divide) ---------------------------------
__global__ void k_fc1(const float* __restrict__ P, const int* __restrict__ start,
                      const float* __restrict__ W, const float* __restrict__ bias,
                      float* __restrict__ out) {
    int row = blockIdx.x >> 2;
    int o = (blockIdx.x & 3) * 256 + threadIdx.x;
    int cnt = start[row + 1] - start[row];
    float scale = 1.0f / fmaxf((float)cnt, 1.0f);
    __shared__ float prow[216];
    if (threadIdx.x < 216) prow[threadIdx.x] = P[row * 216 + threadIdx.x] * scale;
    __syncthreads();
    float acc = bias[o];
    for (int k = 0; k < 216; k++) acc += prow[k] * W[k * 1024 + o];
    out[row * 1024 + o] = fmaxf(acc, 0.f);
}
__global__ void k_fc2(const float* __restrict__ G, const float* __restrict__ W,
                      const float* __restrict__ bias, float* __restrict__ out) {
    int row = blockIdx.x;
    int o = threadIdx.x;  // 128
    __shared__ float grow[1024];
    for (int k = threadIdx.x; k < 1024; k += 128) grow[k] = G[row * 1024 + k];
    __syncthreads();
    float acc = bias[o];
    for (int k = 0; k < 1024; k++) acc += grow[k] * W[k * 128 + o];
    out[row * 128 + o] = acc;
}

// ---------------------------------------------------------------------------
extern "C" void kernel_launch(void* const* d_in, const int* in_sizes, int n_in,
                              void* d_out, int out_size, void* d_ws, size_t ws_size,
                              hipStream_t stream) {
    const float* x     = (const float*)d_in[0];
    const int*   ei    = (const int*)d_in[1];
    const int*   batch = (const int*)d_in[2];
    const float* W1  = (const float*)d_in[3];
    const float* b1  = (const float*)d_in[4];
    const float* W2  = (const float*)d_in[5];
    const float* b2  = (const float*)d_in[6];
    const float* W3  = (const float*)d_in[7];
    const float* b3  = (const float*)d_in[8];
    const float* Wf1 = (const float*)d_in[9];
    const float* bf1 = (const float*)d_in[10];
    const float* Wf2 = (const float*)d_in[11];
    const float* bf2 = (const float*)d_in[12];
    float* out = (float*)d_out;

    const int N = in_sizes[0] / 54;   // 100000
    const int E = in_sizes[1] / 2;    // 1600000
    const int G = 256;
    const int* row = ei;
    const int* col = ei + E;
    const int NCHUNK = cdiv(N, 1024);

    // workspace carve-up (256B aligned)
    char* ws = (char*)d_ws;
    size_t off = 0;
    auto carve = [&](size_t bytes) {
        void* p = ws + off;
        off += (bytes + 255) & ~(size_t)255;
        return p;
    };
    int*   counts    = (int*)carve((size_t)2 * N * 4);
    int*   cursor    = counts + N;
    int*   rowptr    = (int*)carve((size_t)(N + 1) * 4);
    int*   chunkSums = (int*)carve(128 * 4);
    int*   chunkOffs = (int*)carve(128 * 4);
    int*   eSrc      = (int*)carve((size_t)E * 4);
    float* dinv      = (float*)carve((size_t)N * 4);
    float* bufA      = (float*)carve((size_t)N * 108 * 4);
    float* bufB      = (float*)carve((size_t)N * 216 * 4);
    float* psum      = (float*)carve((size_t)G * 216 * 4);
    float* gbuf      = (float*)carve((size_t)G * 1024 * 4);
    int*   start     = (int*)carve((size_t)(G + 1) * 4);

    const int T = 256;

    // ---- CSR build + norms + zeroing ----
    k_zero_int<<<cdiv(2 * N, T), T, 0, stream>>>(counts, 2 * N);
    k_zero_f<<<cdiv(G * 216, T), T, 0, stream>>>(psum, G * 216);
    k_count<<<cdiv(E, T), T, 0, stream>>>(col, counts, E);
    k_scan1<<<NCHUNK, 256, 0, stream>>>(counts, rowptr, chunkSums, N);
    k_scan2<<<1, 128, 0, stream>>>(chunkSums, chunkOffs, NCHUNK);
    k_scan3<<<cdiv(N, T), T, 0, stream>>>(rowptr, chunkOffs, N, E);
    k_dinv<<<cdiv(N, T), T, 0, stream>>>(counts, dinv, N);
    k_fill<<<cdiv(E, T), T, 0, stream>>>(row, col, rowptr, cursor, eSrc, E);

    // ---- graph boundaries ----
    k_init_start<<<cdiv(G + 1, T), T, 0, stream>>>(start, N, G);
    k_find_start<<<cdiv(N, T), T, 0, stream>>>(batch, start, N);

    const int GB = cdiv(N, 72);  // gemm blocks

    // ---- layer 1: a1 = A_hat x ; h1 = relu(a1@W1 + b1) ----
    k_gather<54, 1><<<cdiv(N, 4), 256, 0, stream>>>(rowptr, eSrc, dinv, x, bufA, N);
    k_gemm_lds<54, 54, 2, true><<<GB, 256, 0, stream>>>(bufA, W1, b1, bufB, N);

    // ---- layer 2: a2 = A_hat h1 ; h2 = relu(a2@W2 + b2) ----
    k_gather<54, 1><<<cdiv(N, 4), 256, 0, stream>>>(rowptr, eSrc, dinv, bufB, bufA, N);
    k_gemm_lds<54, 108, 4, true><<<GB, 256, 0, stream>>>(bufA, W2, b2, bufB, N);

    // ---- layer 3: a3 = A_hat h2 ; h3 = relu(a3@W3 + b3) ----
    k_gather<108, 2><<<cdiv(N, 4), 256, 0, stream>>>(rowptr, eSrc, dinv, bufB, bufA, N);
    k_gemm_lds<108, 216, 8, true><<<GB, 256, 0, stream>>>(bufA, W3, b3, bufB, N);

    // ---- mean pool (segmented) + FC head ----
    k_pool<216, 4><<<G * 4, T, 0, stream>>>(bufB, start, psum);
    k_fc1<<<G * 4, T, 0, stream>>>(psum, start, Wf1, bf1, gbuf);
    k_fc2<<<G, 128, 0, stream>>>(gbuf, Wf2, bf2, out);
}

// Round 6
// 723.858 us; speedup vs baseline: 12.4835x; 1.0090x over previous
//
#include <hip/hip_runtime.h>

// ---------------------------------------------------------------------------
// ProteinGCNNet: 3x GCNConv + mean-pool + 2 FC layers, fp32.
// Round 6: (1) prescale trick: hs = dinv*h folded into GEMM epilogue, so the
// gather is a pure row-sum (no per-edge dinv load/FMA); (2) gather edge-unroll
// x8 for 2x memory-level parallelism against L3 latency.
// ---------------------------------------------------------------------------

static __host__ __device__ inline int cdiv(int a, int b) { return (a + b - 1) / b; }

template <int V>
__device__ __forceinline__ void vload(float* d, const float* s) {
    if constexpr (V == 1) { d[0] = s[0]; }
    else if constexpr (V == 2) { float2 t = *reinterpret_cast<const float2*>(s); d[0] = t.x; d[1] = t.y; }
    else if constexpr (V == 4) { float4 t = *reinterpret_cast<const float4*>(s); d[0] = t.x; d[1] = t.y; d[2] = t.z; d[3] = t.w; }
    else { vload<4>(d, s); vload<4>(d + 4, s + 4); }
}
template <int V>
__device__ __forceinline__ void vstore(float* dst, const float* s) {
    if constexpr (V == 1) { dst[0] = s[0]; }
    else if constexpr (V == 2) { *reinterpret_cast<float2*>(dst) = make_float2(s[0], s[1]); }
    else if constexpr (V == 4) { *reinterpret_cast<float4*>(dst) = make_float4(s[0], s[1], s[2], s[3]); }
    else { vstore<4>(dst, s); vstore<4>(dst + 4, s + 4); }
}

// ---- zero ------------------------------------------------------------------
__global__ void k_zero_int(int* p, int n) {
    int i = blockIdx.x * blockDim.x + threadIdx.x;
    if (i < n) p[i] = 0;
}
__global__ void k_zero_f(float* p, int n) {
    int i = blockIdx.x * blockDim.x + threadIdx.x;
    if (i < n) p[i] = 0.f;
}

// ---- in-degree histogram ---------------------------------------------------
__global__ void k_count(const int* __restrict__ col, int* counts, int e) {
    int i = blockIdx.x * blockDim.x + threadIdx.x;
    if (i < e) atomicAdd(&counts[col[i]], 1);
}

// ---- dinv[i] = rsqrt(counts[i] + 1) ----------------------------------------
__global__ void k_dinv(const int* __restrict__ counts, float* __restrict__ dinv, int n) {
    int i = blockIdx.x * blockDim.x + threadIdx.x;
    if (i < n) dinv[i] = rsqrtf((float)(counts[i] + 1));
}

// ---- xs = dinv (x) x  (prescale layer-1 input) ------------------------------
template <int F>
__global__ void k_prescale(const float* __restrict__ x, const float* __restrict__ dinv,
                           float* __restrict__ xs, int n) {
    constexpr int CH = F / 2;
    int idx = blockIdx.x * blockDim.x + threadIdx.x;
    if (idx >= n * CH) return;
    int node = idx / CH;
    int c = idx - node * CH;
    float d = dinv[node];
    float v[2];
    vload<2>(v, x + (long long)node * F + c * 2);
    v[0] *= d; v[1] *= d;
    vstore<2>(xs + (long long)node * F + c * 2, v);
}

// ---- prefix scan of counts -> rowptr (exclusive), chunked ------------------
__global__ void k_scan1(const int* __restrict__ counts, int* __restrict__ rowptr,
                        int* __restrict__ chunkSums, int n) {
    __shared__ int lds[256];
    int b = blockIdx.x, t = threadIdx.x;
    int base = b * 1024 + t * 4;
    int v[4], s = 0;
#pragma unroll
    for (int j = 0; j < 4; j++) {
        v[j] = (base + j < n) ? counts[base + j] : 0;
        s += v[j];
    }
    lds[t] = s;
    __syncthreads();
    for (int off = 1; off < 256; off <<= 1) {
        int x = lds[t];
        int y = (t >= off) ? lds[t - off] : 0;
        __syncthreads();
        lds[t] = x + y;
        __syncthreads();
    }
    int p = lds[t] - s;
#pragma unroll
    for (int j = 0; j < 4; j++) {
        if (base + j < n) rowptr[base + j] = p;
        p += v[j];
    }
    if (t == 255) chunkSums[b] = lds[255];
}

__global__ void k_scan2(const int* __restrict__ chunkSums, int* __restrict__ chunkOffs, int nc) {
    __shared__ int lds[128];
    int t = threadIdx.x;
    int v = (t < nc) ? chunkSums[t] : 0;
    lds[t] = v;
    __syncthreads();
    for (int off = 1; off < 128; off <<= 1) {
        int x = lds[t];
        int y = (t >= off) ? lds[t - off] : 0;
        __syncthreads();
        lds[t] = x + y;
        __syncthreads();
    }
    chunkOffs[t] = lds[t] - v;
}

__global__ void k_scan3(int* rowptr, const int* __restrict__ chunkOffs, int n, int e) {
    int i = blockIdx.x * blockDim.x + threadIdx.x;
    if (i < n) rowptr[i] += chunkOffs[i >> 10];
    if (i == 0) rowptr[n] = e;
}

// ---- CSR fill: eSrc ordered by destination ---------------------------------
__global__ void k_fill(const int* __restrict__ row, const int* __restrict__ col,
                       const int* __restrict__ rowptr, int* cursor, int* __restrict__ eSrc, int e) {
    int i = blockIdx.x * blockDim.x + threadIdx.x;
    if (i >= e) return;
    int c = col[i];
    int pos = atomicAdd(&cursor[c], 1);
    eSrc[rowptr[c] + pos] = row[i];
}

// ---- gather row-sum: out[i] = dinv[i] * (hs[i] + sum_s hs[s]) --------------
// hs is pre-scaled (dinv (x) h). Edge-unroll x8 for MLP.
template <int F, int VEC>
__global__ __launch_bounds__(256) void k_gather(
        const int* __restrict__ rowptr, const int* __restrict__ eSrc,
        const float* __restrict__ dinv, const float* __restrict__ hs,
        float* __restrict__ out, int n) {
    constexpr int CH = F / VEC;
    int wave = threadIdx.x >> 6;
    int lane = threadIdx.x & 63;
    int node = blockIdx.x * (blockDim.x >> 6) + wave;
    if (node >= n || lane >= CH) return;

    float acc[VEC];
    vload<VEC>(acc, hs + (long long)node * F + lane * VEC);

    int rs = rowptr[node], re = rowptr[node + 1];
    int e = rs;
    for (; e + 8 <= re; e += 8) {
        int s[8];
#pragma unroll
        for (int u = 0; u < 8; u++) s[u] = eSrc[e + u];
        float v[8][VEC];
#pragma unroll
        for (int u = 0; u < 8; u++)
            vload<VEC>(v[u], hs + (long long)s[u] * F + lane * VEC);
#pragma unroll
        for (int u = 0; u < 8; u++)
#pragma unroll
            for (int j = 0; j < VEC; j++) acc[j] += v[u][j];
    }
    for (; e < re; e++) {
        int s = eSrc[e];
        float v[VEC];
        vload<VEC>(v, hs + (long long)s * F + lane * VEC);
#pragma unroll
        for (int j = 0; j < VEC; j++) acc[j] += v[j];
    }
    float di = dinv[node];
#pragma unroll
    for (int j = 0; j < VEC; j++) acc[j] *= di;
    vstore<VEC>(out + (long long)node * F + lane * VEC, acc);
}

// ---- LDS-tiled node GEMM ---------------------------------------------------
// out[n,FOUT] = relu(in[n,K] @ W[K,FOUT] + bias) [* dinv[node] if SCALE]
template <int K, int FOUT, int VEC, bool RELU, bool SCALE>
__global__ __launch_bounds__(256) void k_gemm_lds(
        const float* __restrict__ in, const float* __restrict__ W,
        const float* __restrict__ bias, const float* __restrict__ dinv,
        float* __restrict__ out, int n) {
    constexpr int M = 72, NT = 8, CG = FOUT / VEC;  // CG == 27
    constexpr int LROW = 80;                         // 72 + 8 pad
    constexpr int KV = (K % 4 == 0) ? 4 : 2;
    constexpr int GPN = K / KV;
    constexpr int TOT = GPN * M;
    static_assert(CG == 27, "FOUT must be 27*VEC");

    __shared__ float a_lds[K * LROW];

    int t = threadIdx.x;
    int node0 = blockIdx.x * M;

    for (int it = 0; it < (TOT + 255) / 256; it++) {
        int f = t + it * 256;
        if (f < TOT) {
            int node = f / GPN;
            int kq = f - node * GPN;
            float v[KV] = {};
            if (node0 + node < n)
                vload<KV>(v, in + (long long)(node0 + node) * K + kq * KV);
#pragma unroll
            for (int j = 0; j < KV; j++)
                a_lds[(kq * KV + j) * LROW + node] = v[j];
        }
    }
    __syncthreads();

    if (t >= 243) return;
    int cg = t % 27;
    int strip = t / 27;

    float acc[NT][VEC];
#pragma unroll
    for (int i = 0; i < NT; i++)
#pragma unroll
        for (int j = 0; j < VEC; j++) acc[i][j] = 0.f;

    const float* wp = W + cg * VEC;
    for (int k = 0; k < K; k++) {
        float w[VEC];
        vload<VEC>(w, wp + k * FOUT);
        float av[NT];
        vload<NT>(av, &a_lds[k * LROW + strip * NT]);
#pragma unroll
        for (int i = 0; i < NT; i++)
#pragma unroll
            for (int j = 0; j < VEC; j++) acc[i][j] += av[i] * w[j];
    }

    float bv[VEC];
    vload<VEC>(bv, bias + cg * VEC);
#pragma unroll
    for (int i = 0; i < NT; i++) {
        int node = node0 + strip * NT + i;
        if (node >= n) break;
        float sc = SCALE ? dinv[node] : 1.0f;
        float o[VEC];
#pragma unroll
        for (int j = 0; j < VEC; j++) {
            o[j] = acc[i][j] + bv[j];
            if (RELU) o[j] = fmaxf(o[j], 0.f);
            if (SCALE) o[j] *= sc;
        }
        vstore<VEC>(out + (long long)node * FOUT + cg * VEC, o);
    }
}

// ---- per-graph boundaries (batch sorted ascending) -------------------------
__global__ void k_init_start(int* start, int n, int g) {
    int i = blockIdx.x * blockDim.x + threadIdx.x;
    if (i <= g) start[i] = n;
}
__global__ void k_find_start(const int* __restrict__ batch, int* start, int n) {
    int i = blockIdx.x * blockDim.x + threadIdx.x;
    if (i >= n) return;
    int b = batch[i];
    int bp = (i == 0) ? -1 : batch[i - 1];
    for (int g = bp + 1; g <= b; g++) start[g] = i;
}

// ---- segmented mean-pool: psum[g,f] += sum over node segment ---------------
template <int F, int NSEG>
__global__ void k_pool(const float* __restrict__ h, const int* __restrict__ start,
                       float* __restrict__ psum) {
    int g = blockIdx.x / NSEG;
    int seg = blockIdx.x - g * NSEG;
    int f = threadIdx.x;
    if (f >= F) return;
    int s = start[g], e = start[g + 1];
    int len = e - s;
    int chunk = (len + NSEG - 1) / NSEG;
    int cs = s + seg * chunk;
    int ce = cs + chunk < e ? cs + chunk : e;
    if (cs >= ce) return;
    float acc = 0.f;
    for (int nd = cs; nd < ce; nd++) acc += h[(long long)nd * F + f];
    atomicAdd(&psum[g * F + f], acc);
}

// ---- FC layers (fc1 folds the mean divide) ---------------------------------
__global__ void k_fc1(const float* __restrict__ P, const int* __restrict__ start,
                      const float* __restrict__ W, const float* __restrict__ bias,
                      float* __restrict__ out) {
    int row = blockIdx.x >> 2;
    int o = (blockIdx.x & 3) * 256 + threadIdx.x;
    int cnt = start[row + 1] - start[row];
    float scale = 1.0f / fmaxf((float)cnt, 1.0f);
    __shared__ float prow[216];
    if (threadIdx.x < 216) prow[threadIdx.x] = P[row * 216 + threadIdx.x] * scale;
    __syncthreads();
    float acc = bias[o];
    for (int k = 0; k < 216; k++) acc += prow[k] * W[k * 1024 + o];
    out[row * 1024 + o] = fmaxf(acc, 0.f);
}
__global__ void k_fc2(const float* __restrict__ G, const float* __restrict__ W,
                      const float* __restrict__ bias, float* __restrict__ out) {
    int row = blockIdx.x;
    int o = threadIdx.x;  // 128
    __shared__ float grow[1024];
    for (int k = threadIdx.x; k < 1024; k += 128) grow[k] = G[row * 1024 + k];
    __syncthreads();
    float acc = bias[o];
    for (int k = 0; k < 1024; k++) acc += grow[k] * W[k * 128 + o];
    out[row * 128 + o] = acc;
}

// ---------------------------------------------------------------------------
extern "C" void kernel_launch(void* const* d_in, const int* in_sizes, int n_in,
                              void* d_out, int out_size, void* d_ws, size_t ws_size,
                              hipStream_t stream) {
    const float* x     = (const float*)d_in[0];
    const int*   ei    = (const int*)d_in[1];
    const int*   batch = (const int*)d_in[2];
    const float* W1  = (const float*)d_in[3];
    const float* b1  = (const float*)d_in[4];
    const float* W2  = (const float*)d_in[5];
    const float* b2  = (const float*)d_in[6];
    const float* W3  = (const float*)d_in[7];
    const float* b3  = (const float*)d_in[8];
    const float* Wf1 = (const float*)d_in[9];
    const float* bf1 = (const float*)d_in[10];
    const float* Wf2 = (const float*)d_in[11];
    const float* bf2 = (const float*)d_in[12];
    float* out = (float*)d_out;

    const int N = in_sizes[0] / 54;   // 100000
    const int E = in_sizes[1] / 2;    // 1600000
    const int G = 256;
    const int* row = ei;
    const int* col = ei + E;
    const int NCHUNK = cdiv(N, 1024);

    // workspace carve-up (256B aligned)
    char* ws = (char*)d_ws;
    size_t off = 0;
    auto carve = [&](size_t bytes) {
        void* p = ws + off;
        off += (bytes + 255) & ~(size_t)255;
        return p;
    };
    int*   counts    = (int*)carve((size_t)2 * N * 4);
    int*   cursor    = counts + N;
    int*   rowptr    = (int*)carve((size_t)(N + 1) * 4);
    int*   chunkSums = (int*)carve(128 * 4);
    int*   chunkOffs = (int*)carve(128 * 4);
    int*   eSrc      = (int*)carve((size_t)E * 4);
    float* dinv      = (float*)carve((size_t)N * 4);
    float* xs        = (float*)carve((size_t)N * 54 * 4);
    float* bufA      = (float*)carve((size_t)N * 108 * 4);
    float* bufB      = (float*)carve((size_t)N * 216 * 4);
    float* psum      = (float*)carve((size_t)G * 216 * 4);
    float* gbuf      = (float*)carve((size_t)G * 1024 * 4);
    int*   start     = (int*)carve((size_t)(G + 1) * 4);

    const int T = 256;

    // ---- CSR build + norms + zeroing ----
    k_zero_int<<<cdiv(2 * N, T), T, 0, stream>>>(counts, 2 * N);
    k_zero_f<<<cdiv(G * 216, T), T, 0, stream>>>(psum, G * 216);
    k_count<<<cdiv(E, T), T, 0, stream>>>(col, counts, E);
    k_scan1<<<NCHUNK, 256, 0, stream>>>(counts, rowptr, chunkSums, N);
    k_scan2<<<1, 128, 0, stream>>>(chunkSums, chunkOffs, NCHUNK);
    k_scan3<<<cdiv(N, T), T, 0, stream>>>(rowptr, chunkOffs, N, E);
    k_dinv<<<cdiv(N, T), T, 0, stream>>>(counts, dinv, N);
    k_fill<<<cdiv(E, T), T, 0, stream>>>(row, col, rowptr, cursor, eSrc, E);
    k_prescale<54><<<cdiv(N * 27, T), T, 0, stream>>>(x, dinv, xs, N);

    // ---- graph boundaries ----
    k_init_start<<<cdiv(G + 1, T), T, 0, stream>>>(start, N, G);
    k_find_start<<<cdiv(N, T), T, 0, stream>>>(batch, start, N);

    const int GB = cdiv(N, 72);  // gemm blocks

    // ---- layer 1: a1 = A_hat x ; hs1 = dinv*relu(a1@W1 + b1) ----
    k_gather<54, 1><<<cdiv(N, 4), 256, 0, stream>>>(rowptr, eSrc, dinv, xs, bufA, N);
    k_gemm_lds<54, 54, 2, true, true><<<GB, 256, 0, stream>>>(bufA, W1, b1, dinv, bufB, N);

    // ---- layer 2: a2 = A_hat h1 (via hs1) ; hs2 = dinv*relu(a2@W2 + b2) ----
    k_gather<54, 1><<<cdiv(N, 4), 256, 0, stream>>>(rowptr, eSrc, dinv, bufB, bufA, N);
    k_gemm_lds<54, 108, 4, true, true><<<GB, 256, 0, stream>>>(bufA, W2, b2, dinv, bufB, N);

    // ---- layer 3: a3 = A_hat h2 (via hs2) ; h3 = relu(a3@W3 + b3) ----
    k_gather<108, 2><<<cdiv(N, 4), 256, 0, stream>>>(rowptr, eSrc, dinv, bufB, bufA, N);
    k_gemm_lds<108, 216, 8, true, false><<<GB, 256, 0, stream>>>(bufA, W3, b3, nullptr, bufB, N);

    // ---- mean pool (segmented) + FC head ----
    k_pool<216, 4><<<G * 4, T, 0, stream>>>(bufB, start, psum);
    k_fc1<<<G * 4, T, 0, stream>>>(psum, start, Wf1, bf1, gbuf);
    k_fc2<<<G, 128, 0, stream>>>(gbuf, Wf2, bf2, out);
}

// Round 7
// 694.559 us; speedup vs baseline: 13.0101x; 1.0422x over previous
//
#include <hip/hip_runtime.h>

// ---------------------------------------------------------------------------
// ProteinGCNNet: 3x GCNConv + mean-pool + 2 FC layers.
// Round 7: fp16 storage for gather operands (fp32 accumulate). The gathers are
// L3-traffic bound (412 MB @ ~3.9 TB/s, VALUBusy 10%); halving bytes is the
// only lever left. GEMM math, pool, FC all stay fp32.
// ---------------------------------------------------------------------------

typedef _Float16 f16;
typedef _Float16 f16x2 __attribute__((ext_vector_type(2)));
typedef _Float16 f16x4 __attribute__((ext_vector_type(4)));

static __host__ __device__ inline int cdiv(int a, int b) { return (a + b - 1) / b; }

template <int V>
__device__ __forceinline__ void vload(float* d, const float* s) {
    if constexpr (V == 1) { d[0] = s[0]; }
    else if constexpr (V == 2) { float2 t = *reinterpret_cast<const float2*>(s); d[0] = t.x; d[1] = t.y; }
    else if constexpr (V == 4) { float4 t = *reinterpret_cast<const float4*>(s); d[0] = t.x; d[1] = t.y; d[2] = t.z; d[3] = t.w; }
    else { vload<4>(d, s); vload<4>(d + 4, s + 4); }
}
template <int V>
__device__ __forceinline__ void vstore(float* dst, const float* s) {
    if constexpr (V == 1) { dst[0] = s[0]; }
    else if constexpr (V == 2) { *reinterpret_cast<float2*>(dst) = make_float2(s[0], s[1]); }
    else if constexpr (V == 4) { *reinterpret_cast<float4*>(dst) = make_float4(s[0], s[1], s[2], s[3]); }
    else { vstore<4>(dst, s); vstore<4>(dst + 4, s + 4); }
}

// ---- zero ------------------------------------------------------------------
__global__ void k_zero_int(int* p, int n) {
    int i = blockIdx.x * blockDim.x + threadIdx.x;
    if (i < n) p[i] = 0;
}
__global__ void k_zero_f(float* p, int n) {
    int i = blockIdx.x * blockDim.x + threadIdx.x;
    if (i < n) p[i] = 0.f;
}

// ---- in-degree histogram ---------------------------------------------------
__global__ void k_count(const int* __restrict__ col, int* counts, int e) {
    int i = blockIdx.x * blockDim.x + threadIdx.x;
    if (i < e) atomicAdd(&counts[col[i]], 1);
}

// ---- dinv[i] = rsqrt(counts[i] + 1) ----------------------------------------
__global__ void k_dinv(const int* __restrict__ counts, float* __restrict__ dinv, int n) {
    int i = blockIdx.x * blockDim.x + threadIdx.x;
    if (i < n) dinv[i] = rsqrtf((float)(counts[i] + 1));
}

// ---- xs = f16(dinv (x) x)  (prescale layer-1 input) -------------------------
template <int F>
__global__ void k_prescale(const float* __restrict__ x, const float* __restrict__ dinv,
                           f16* __restrict__ xs, int n) {
    constexpr int CH = F / 2;
    int idx = blockIdx.x * blockDim.x + threadIdx.x;
    if (idx >= n * CH) return;
    int node = idx / CH;
    int c = idx - node * CH;
    float d = dinv[node];
    float v[2];
    vload<2>(v, x + (long long)node * F + c * 2);
    f16x2 h;
    h[0] = (f16)(v[0] * d);
    h[1] = (f16)(v[1] * d);
    *reinterpret_cast<f16x2*>(xs + (long long)node * F + c * 2) = h;
}

// ---- prefix scan of counts -> rowptr (exclusive), chunked ------------------
__global__ void k_scan1(const int* __restrict__ counts, int* __restrict__ rowptr,
                        int* __restrict__ chunkSums, int n) {
    __shared__ int lds[256];
    int b = blockIdx.x, t = threadIdx.x;
    int base = b * 1024 + t * 4;
    int v[4], s = 0;
#pragma unroll
    for (int j = 0; j < 4; j++) {
        v[j] = (base + j < n) ? counts[base + j] : 0;
        s += v[j];
    }
    lds[t] = s;
    __syncthreads();
    for (int off = 1; off < 256; off <<= 1) {
        int x = lds[t];
        int y = (t >= off) ? lds[t - off] : 0;
        __syncthreads();
        lds[t] = x + y;
        __syncthreads();
    }
    int p = lds[t] - s;
#pragma unroll
    for (int j = 0; j < 4; j++) {
        if (base + j < n) rowptr[base + j] = p;
        p += v[j];
    }
    if (t == 255) chunkSums[b] = lds[255];
}

__global__ void k_scan2(const int* __restrict__ chunkSums, int* __restrict__ chunkOffs, int nc) {
    __shared__ int lds[128];
    int t = threadIdx.x;
    int v = (t < nc) ? chunkSums[t] : 0;
    lds[t] = v;
    __syncthreads();
    for (int off = 1; off < 128; off <<= 1) {
        int x = lds[t];
        int y = (t >= off) ? lds[t - off] : 0;
        __syncthreads();
        lds[t] = x + y;
        __syncthreads();
    }
    chunkOffs[t] = lds[t] - v;
}

__global__ void k_scan3(int* rowptr, const int* __restrict__ chunkOffs, int n, int e) {
    int i = blockIdx.x * blockDim.x + threadIdx.x;
    if (i < n) rowptr[i] += chunkOffs[i >> 10];
    if (i == 0) rowptr[n] = e;
}

// ---- CSR fill: eSrc ordered by destination ---------------------------------
__global__ void k_fill(const int* __restrict__ row, const int* __restrict__ col,
                       const int* __restrict__ rowptr, int* cursor, int* __restrict__ eSrc, int e) {
    int i = blockIdx.x * blockDim.x + threadIdx.x;
    if (i >= e) return;
    int c = col[i];
    int pos = atomicAdd(&cursor[c], 1);
    eSrc[rowptr[c] + pos] = row[i];
}

// ---- gather row-sum (fp16 in, fp32 out) ------------------------------------
// out[i] = dinv[i] * (hs[i] + sum_s hs[s]); hs pre-scaled by dinv.
template <int F>
__global__ __launch_bounds__(256) void k_gather(
        const int* __restrict__ rowptr, const int* __restrict__ eSrc,
        const float* __restrict__ dinv, const f16* __restrict__ hs,
        float* __restrict__ out, int n) {
    constexpr int CH = F / 2;
    int wave = threadIdx.x >> 6;
    int lane = threadIdx.x & 63;
    int node = blockIdx.x * (blockDim.x >> 6) + wave;
    if (node >= n || lane >= CH) return;

    f16x2 sv = *reinterpret_cast<const f16x2*>(hs + (long long)node * F + lane * 2);
    float acc0 = (float)sv[0], acc1 = (float)sv[1];

    int rs = rowptr[node], re = rowptr[node + 1];
    int e = rs;
    for (; e + 8 <= re; e += 8) {
        int s[8];
#pragma unroll
        for (int u = 0; u < 8; u++) s[u] = eSrc[e + u];
        f16x2 v[8];
#pragma unroll
        for (int u = 0; u < 8; u++)
            v[u] = *reinterpret_cast<const f16x2*>(hs + (long long)s[u] * F + lane * 2);
#pragma unroll
        for (int u = 0; u < 8; u++) {
            acc0 += (float)v[u][0];
            acc1 += (float)v[u][1];
        }
    }
    for (; e < re; e++) {
        int s = eSrc[e];
        f16x2 v = *reinterpret_cast<const f16x2*>(hs + (long long)s * F + lane * 2);
        acc0 += (float)v[0];
        acc1 += (float)v[1];
    }
    float di = dinv[node];
    *reinterpret_cast<float2*>(out + (long long)node * F + lane * 2) =
        make_float2(acc0 * di, acc1 * di);
}

// ---- LDS-tiled node GEMM ---------------------------------------------------
// out = relu(in[n,K] @ W[K,FOUT] + bias) [* dinv if SCALE]; fp32 or fp16 out.
template <int K, int FOUT, int VEC, bool RELU, bool SCALE, bool OUTH>
__global__ __launch_bounds__(256) void k_gemm_lds(
        const float* __restrict__ in, const float* __restrict__ W,
        const float* __restrict__ bias, const float* __restrict__ dinv,
        float* __restrict__ outf, f16* __restrict__ outh, int n) {
    constexpr int M = 72, NT = 8, CG = FOUT / VEC;  // CG == 27
    constexpr int LROW = 80;
    constexpr int KV = (K % 4 == 0) ? 4 : 2;
    constexpr int GPN = K / KV;
    constexpr int TOT = GPN * M;
    static_assert(CG == 27, "FOUT must be 27*VEC");

    __shared__ float a_lds[K * LROW];

    int t = threadIdx.x;
    int node0 = blockIdx.x * M;

    for (int it = 0; it < (TOT + 255) / 256; it++) {
        int f = t + it * 256;
        if (f < TOT) {
            int node = f / GPN;
            int kq = f - node * GPN;
            float v[KV] = {};
            if (node0 + node < n)
                vload<KV>(v, in + (long long)(node0 + node) * K + kq * KV);
#pragma unroll
            for (int j = 0; j < KV; j++)
                a_lds[(kq * KV + j) * LROW + node] = v[j];
        }
    }
    __syncthreads();

    if (t >= 243) return;
    int cg = t % 27;
    int strip = t / 27;

    float acc[NT][VEC];
#pragma unroll
    for (int i = 0; i < NT; i++)
#pragma unroll
        for (int j = 0; j < VEC; j++) acc[i][j] = 0.f;

    const float* wp = W + cg * VEC;
    for (int k = 0; k < K; k++) {
        float w[VEC];
        vload<VEC>(w, wp + k * FOUT);
        float av[NT];
        vload<NT>(av, &a_lds[k * LROW + strip * NT]);
#pragma unroll
        for (int i = 0; i < NT; i++)
#pragma unroll
            for (int j = 0; j < VEC; j++) acc[i][j] += av[i] * w[j];
    }

    float bv[VEC];
    vload<VEC>(bv, bias + cg * VEC);
#pragma unroll
    for (int i = 0; i < NT; i++) {
        int node = node0 + strip * NT + i;
        if (node >= n) break;
        float sc = SCALE ? dinv[node] : 1.0f;
        float o[VEC];
#pragma unroll
        for (int j = 0; j < VEC; j++) {
            o[j] = acc[i][j] + bv[j];
            if (RELU) o[j] = fmaxf(o[j], 0.f);
            if (SCALE) o[j] *= sc;
        }
        if constexpr (OUTH) {
            if constexpr (VEC == 2) {
                f16x2 h; h[0] = (f16)o[0]; h[1] = (f16)o[1];
                *reinterpret_cast<f16x2*>(outh + (long long)node * FOUT + cg * VEC) = h;
            } else {
                f16x4 h;
#pragma unroll
                for (int j = 0; j < 4; j++) h[j] = (f16)o[j];
                *reinterpret_cast<f16x4*>(outh + (long long)node * FOUT + cg * VEC) = h;
            }
        } else {
            vstore<VEC>(outf + (long long)node * FOUT + cg * VEC, o);
        }
    }
}

// ---- per-graph boundaries (batch sorted ascending) -------------------------
__global__ void k_init_start(int* start, int n, int g) {
    int i = blockIdx.x * blockDim.x + threadIdx.x;
    if (i <= g) start[i] = n;
}
__global__ void k_find_start(const int* __restrict__ batch, int* start, int n) {
    int i = blockIdx.x * blockDim.x + threadIdx.x;
    if (i >= n) return;
    int b = batch[i];
    int bp = (i == 0) ? -1 : batch[i - 1];
    for (int g = bp + 1; g <= b; g++) start[g] = i;
}

// ---- segmented mean-pool ----------------------------------------------------
template <int F, int NSEG>
__global__ void k_pool(const float* __restrict__ h, const int* __restrict__ start,
                       float* __restrict__ psum) {
    int g = blockIdx.x / NSEG;
    int seg = blockIdx.x - g * NSEG;
    int f = threadIdx.x;
    if (f >= F) return;
    int s = start[g], e = start[g + 1];
    int len = e - s;
    int chunk = (len + NSEG - 1) / NSEG;
    int cs = s + seg * chunk;
    int ce = cs + chunk < e ? cs + chunk : e;
    if (cs >= ce) return;
    float acc = 0.f;
    for (int nd = cs; nd < ce; nd++) acc += h[(long long)nd * F + f];
    atomicAdd(&psum[g * F + f], acc);
}

// ---- FC layers (fc1 folds the mean divide) ---------------------------------
__global__ void k_fc1(const float* __restrict__ P, const int* __restrict__ start,
                      const float* __restrict__ W, const float* __restrict__ bias,
                      float* __restrict__ out) {
    int row = blockIdx.x >> 2;
    int o = (blockIdx.x & 3) * 256 + threadIdx.x;
    int cnt = start[row + 1] - start[row];
    float scale = 1.0f / fmaxf((float)cnt, 1.0f);
    __shared__ float prow[216];
    if (threadIdx.x < 216) prow[threadIdx.x] = P[row * 216 + threadIdx.x] * scale;
    __syncthreads();
    float acc = bias[o];
    for (int k = 0; k < 216; k++) acc += prow[k] * W[k * 1024 + o];
    out[row * 1024 + o] = fmaxf(acc, 0.f);
}
__global__ void k_fc2(const float* __restrict__ G, const float* __restrict__ W,
                      const float* __restrict__ bias, float* __restrict__ out) {
    int row = blockIdx.x;
    int o = threadIdx.x;  // 128
    __shared__ float grow[1024];
    for (int k = threadIdx.x; k < 1024; k += 128) grow[k] = G[row * 1024 + k];
    __syncthreads();
    float acc = bias[o];
    for (int k = 0; k < 1024; k++) acc += grow[k] * W[k * 128 + o];
    out[row * 128 + o] = acc;
}

// ---------------------------------------------------------------------------
extern "C" void kernel_launch(void* const* d_in, const int* in_sizes, int n_in,
                              void* d_out, int out_size, void* d_ws, size_t ws_size,
                              hipStream_t stream) {
    const float* x     = (const float*)d_in[0];
    const int*   ei    = (const int*)d_in[1];
    const int*   batch = (const int*)d_in[2];
    const float* W1  = (const float*)d_in[3];
    const float* b1  = (const float*)d_in[4];
    const float* W2  = (const float*)d_in[5];
    const float* b2  = (const float*)d_in[6];
    const float* W3  = (const float*)d_in[7];
    const float* b3  = (const float*)d_in[8];
    const float* Wf1 = (const float*)d_in[9];
    const float* bf1 = (const float*)d_in[10];
    const float* Wf2 = (const float*)d_in[11];
    const float* bf2 = (const float*)d_in[12];
    float* out = (float*)d_out;

    const int N = in_sizes[0] / 54;   // 100000
    const int E = in_sizes[1] / 2;    // 1600000
    const int G = 256;
    const int* row = ei;
    const int* col = ei + E;
    const int NCHUNK = cdiv(N, 1024);

    // workspace carve-up (256B aligned)
    char* ws = (char*)d_ws;
    size_t off = 0;
    auto carve = [&](size_t bytes) {
        void* p = ws + off;
        off += (bytes + 255) & ~(size_t)255;
        return p;
    };
    int*   counts    = (int*)carve((size_t)2 * N * 4);
    int*   cursor    = counts + N;
    int*   rowptr    = (int*)carve((size_t)(N + 1) * 4);
    int*   chunkSums = (int*)carve(128 * 4);
    int*   chunkOffs = (int*)carve(128 * 4);
    int*   eSrc      = (int*)carve((size_t)E * 4);
    float* dinv      = (float*)carve((size_t)N * 4);
    f16*   xs        = (f16*)carve((size_t)N * 54 * 2);
    f16*   hsbuf     = (f16*)carve((size_t)N * 108 * 2);   // fp16 gemm outputs
    float* bufA      = (float*)carve((size_t)N * 108 * 4); // fp32 gather outputs
    float* bufB      = (float*)carve((size_t)N * 216 * 4); // fp32 h3
    float* psum      = (float*)carve((size_t)G * 216 * 4);
    float* gbuf      = (float*)carve((size_t)G * 1024 * 4);
    int*   start     = (int*)carve((size_t)(G + 1) * 4);

    const int T = 256;

    // ---- CSR build + norms + zeroing ----
    k_zero_int<<<cdiv(2 * N, T), T, 0, stream>>>(counts, 2 * N);
    k_zero_f<<<cdiv(G * 216, T), T, 0, stream>>>(psum, G * 216);
    k_count<<<cdiv(E, T), T, 0, stream>>>(col, counts, E);
    k_scan1<<<NCHUNK, 256, 0, stream>>>(counts, rowptr, chunkSums, N);
    k_scan2<<<1, 128, 0, stream>>>(chunkSums, chunkOffs, NCHUNK);
    k_scan3<<<cdiv(N, T), T, 0, stream>>>(rowptr, chunkOffs, N, E);
    k_dinv<<<cdiv(N, T), T, 0, stream>>>(counts, dinv, N);
    k_fill<<<cdiv(E, T), T, 0, stream>>>(row, col, rowptr, cursor, eSrc, E);
    k_prescale<54><<<cdiv(N * 27, T), T, 0, stream>>>(x, dinv, xs, N);

    // ---- graph boundaries ----
    k_init_start<<<cdiv(G + 1, T), T, 0, stream>>>(start, N, G);
    k_find_start<<<cdiv(N, T), T, 0, stream>>>(batch, start, N);

    const int GB = cdiv(N, 72);

    // ---- layer 1: a1 = A_hat x ; hs1 = f16(dinv*relu(a1@W1 + b1)) ----
    k_gather<54><<<cdiv(N, 4), 256, 0, stream>>>(rowptr, eSrc, dinv, xs, bufA, N);
    k_gemm_lds<54, 54, 2, true, true, true><<<GB, 256, 0, stream>>>(bufA, W1, b1, dinv, nullptr, hsbuf, N);

    // ---- layer 2: a2 = A_hat h1 ; hs2 = f16(dinv*relu(a2@W2 + b2)) ----
    k_gather<54><<<cdiv(N, 4), 256, 0, stream>>>(rowptr, eSrc, dinv, hsbuf, bufA, N);
    k_gemm_lds<54, 108, 4, true, true, true><<<GB, 256, 0, stream>>>(bufA, W2, b2, dinv, nullptr, hsbuf, N);

    // ---- layer 3: a3 = A_hat h2 ; h3 = relu(a3@W3 + b3) (fp32) ----
    k_gather<108><<<cdiv(N, 4), 256, 0, stream>>>(rowptr, eSrc, dinv, hsbuf, bufA, N);
    k_gemm_lds<108, 216, 8, true, false, false><<<GB, 256, 0, stream>>>(bufA, W3, b3, nullptr, bufB, nullptr, N);

    // ---- mean pool (segmented) + FC head ----
    k_pool<216, 4><<<G * 4, T, 0, stream>>>(bufB, start, psum);
    k_fc1<<<G * 4, T, 0, stream>>>(psum, start, Wf1, bf1, gbuf);
    k_fc2<<<G, 128, 0, stream>>>(gbuf, Wf2, bf2, out);
}

// Round 8
// 581.776 us; speedup vs baseline: 15.5322x; 1.1939x over previous
//
#include <hip/hip_runtime.h>

// ---------------------------------------------------------------------------
// ProteinGCNNet: 3x GCNConv + mean-pool + 2 FC layers.
// Round 8: bucketed edge sort replaces atomic count+fill. Buckets of 512 dst
// nodes; per-bucket workgroups make all eSrc/counts writes single-CU-local ->
// full-line L2 fills instead of 16x write-amplified random scatter.
// fp16 gather storage (fp32 accumulate) kept from round 7.
// ---------------------------------------------------------------------------

typedef _Float16 f16;
typedef _Float16 f16x2 __attribute__((ext_vector_type(2)));
typedef _Float16 f16x4 __attribute__((ext_vector_type(4)));

static __host__ __device__ inline int cdiv(int a, int b) { return (a + b - 1) / b; }

constexpr int BSPAN = 512;   // dst nodes per bucket (col >> 9)
constexpr int EPB   = 4096;  // edges per partition block
constexpr int EPT   = EPB / 256;  // 16 edges per thread

template <int V>
__device__ __forceinline__ void vload(float* d, const float* s) {
    if constexpr (V == 1) { d[0] = s[0]; }
    else if constexpr (V == 2) { float2 t = *reinterpret_cast<const float2*>(s); d[0] = t.x; d[1] = t.y; }
    else if constexpr (V == 4) { float4 t = *reinterpret_cast<const float4*>(s); d[0] = t.x; d[1] = t.y; d[2] = t.z; d[3] = t.w; }
    else { vload<4>(d, s); vload<4>(d + 4, s + 4); }
}
template <int V>
__device__ __forceinline__ void vstore(float* dst, const float* s) {
    if constexpr (V == 1) { dst[0] = s[0]; }
    else if constexpr (V == 2) { *reinterpret_cast<float2*>(dst) = make_float2(s[0], s[1]); }
    else if constexpr (V == 4) { *reinterpret_cast<float4*>(dst) = make_float4(s[0], s[1], s[2], s[3]); }
    else { vstore<4>(dst, s); vstore<4>(dst + 4, s + 4); }
}

// ---- zero psum (float) + bktCnt (int) in one kernel ------------------------
__global__ void k_zero2(float* pf, int nf, int* pi, int ni) {
    int i = blockIdx.x * blockDim.x + threadIdx.x;
    if (i < nf) pf[i] = 0.f;
    if (i < ni) pi[i] = 0;
}

// ---- A1: per-block LDS bucket histogram -> global bucket counts ------------
__global__ __launch_bounds__(256) void k_bkt_hist(const int* __restrict__ col,
                                                  int* bktCnt, int e, int nb) {
    __shared__ int hist[256];
    int t = threadIdx.x;
    hist[t] = 0;
    __syncthreads();
    int base = blockIdx.x * EPB;
#pragma unroll
    for (int j = 0; j < EPT; j++) {
        int idx = base + j * 256 + t;
        if (idx < e) atomicAdd(&hist[col[idx] >> 9], 1);
    }
    __syncthreads();
    if (t < nb && hist[t] > 0) atomicAdd(&bktCnt[t], hist[t]);
}

// ---- A-scan: exclusive scan of bucket counts -> bktOff, bktCur -------------
__global__ void k_bkt_scan(const int* __restrict__ bktCnt, int* __restrict__ bktOff,
                           int* __restrict__ bktCur, int nb, int e) {
    __shared__ int lds[256];
    int t = threadIdx.x;
    int v = (t < nb) ? bktCnt[t] : 0;
    lds[t] = v;
    __syncthreads();
    for (int off = 1; off < 256; off <<= 1) {
        int x = lds[t];
        int y = (t >= off) ? lds[t - off] : 0;
        __syncthreads();
        lds[t] = x + y;
        __syncthreads();
    }
    int ex = lds[t] - v;
    if (t < nb) { bktOff[t] = ex; bktCur[t] = ex; }
    if (t == 0) bktOff[nb] = e;
}

// ---- A2: partition edges into bucket-contiguous (col,row) pairs ------------
__global__ __launch_bounds__(256) void k_bkt_part(const int* __restrict__ row,
                                                  const int* __restrict__ col,
                                                  int* bktCur, int2* __restrict__ ebuf,
                                                  int e, int nb) {
    __shared__ int hist[256];
    __shared__ int base[256];
    __shared__ int lcur[256];
    int t = threadIdx.x;
    hist[t] = 0; lcur[t] = 0;
    __syncthreads();
    int bs = blockIdx.x * EPB;
    int r[EPT], c[EPT], b[EPT];
#pragma unroll
    for (int j = 0; j < EPT; j++) {
        int idx = bs + j * 256 + t;
        if (idx < e) {
            c[j] = col[idx]; r[j] = row[idx]; b[j] = c[j] >> 9;
            atomicAdd(&hist[b[j]], 1);
        } else b[j] = -1;
    }
    __syncthreads();
    if (t < nb && hist[t] > 0) base[t] = atomicAdd(&bktCur[t], hist[t]);
    __syncthreads();
#pragma unroll
    for (int j = 0; j < EPT; j++) {
        if (b[j] >= 0) {
            int lofs = atomicAdd(&lcur[b[j]], 1);
            ebuf[base[b[j]] + lofs] = make_int2(c[j], r[j]);
        }
    }
}

// ---- B1: per-bucket node histogram -> counts + dinv (coalesced writes) -----
__global__ __launch_bounds__(256) void k_bkt_count(const int2* __restrict__ ebuf,
                                                   const int* __restrict__ bktOff,
                                                   int* __restrict__ counts,
                                                   float* __restrict__ dinv, int n) {
    __shared__ int hist[BSPAN];
    int t = threadIdx.x;
    int bkt = blockIdx.x;
    hist[t] = 0; hist[t + 256] = 0;
    __syncthreads();
    int es = bktOff[bkt], ee = bktOff[bkt + 1];
    for (int e = es + t; e < ee; e += 256)
        atomicAdd(&hist[ebuf[e].x & (BSPAN - 1)], 1);
    __syncthreads();
    int node0 = bkt * BSPAN;
    for (int i = t; i < BSPAN; i += 256) {
        int node = node0 + i;
        if (node < n) {
            int cv = hist[i];
            counts[node] = cv;
            dinv[node] = rsqrtf((float)(cv + 1));
        }
    }
}

// ---- B2: per-bucket CSR fill with LDS cursors (single-CU-local writes) -----
__global__ __launch_bounds__(256) void k_bkt_fill(const int2* __restrict__ ebuf,
                                                  const int* __restrict__ bktOff,
                                                  const int* __restrict__ rowptr,
                                                  int* __restrict__ eSrc, int n) {
    __shared__ int cur[BSPAN];
    int t = threadIdx.x;
    int bkt = blockIdx.x;
    int node0 = bkt * BSPAN;
    for (int i = t; i < BSPAN; i += 256) {
        int node = node0 + i;
        cur[i] = (node < n) ? rowptr[node] : 0;
    }
    __syncthreads();
    int es = bktOff[bkt], ee = bktOff[bkt + 1];
    for (int e = es + t; e < ee; e += 256) {
        int2 p = ebuf[e];
        int slot = atomicAdd(&cur[p.x & (BSPAN - 1)], 1);
        eSrc[slot] = p.y;
    }
}

// ---- prefix scan of counts -> rowptr (exclusive), chunked ------------------
__global__ void k_scan1(const int* __restrict__ counts, int* __restrict__ rowptr,
                        int* __restrict__ chunkSums, int n) {
    __shared__ int lds[256];
    int b = blockIdx.x, t = threadIdx.x;
    int base = b * 1024 + t * 4;
    int v[4], s = 0;
#pragma unroll
    for (int j = 0; j < 4; j++) {
        v[j] = (base + j < n) ? counts[base + j] : 0;
        s += v[j];
    }
    lds[t] = s;
    __syncthreads();
    for (int off = 1; off < 256; off <<= 1) {
        int x = lds[t];
        int y = (t >= off) ? lds[t - off] : 0;
        __syncthreads();
        lds[t] = x + y;
        __syncthreads();
    }
    int p = lds[t] - s;
#pragma unroll
    for (int j = 0; j < 4; j++) {
        if (base + j < n) rowptr[base + j] = p;
        p += v[j];
    }
    if (t == 255) chunkSums[b] = lds[255];
}

__global__ void k_scan2(const int* __restrict__ chunkSums, int* __restrict__ chunkOffs, int nc) {
    __shared__ int lds[128];
    int t = threadIdx.x;
    int v = (t < nc) ? chunkSums[t] : 0;
    lds[t] = v;
    __syncthreads();
    for (int off = 1; off < 128; off <<= 1) {
        int x = lds[t];
        int y = (t >= off) ? lds[t - off] : 0;
        __syncthreads();
        lds[t] = x + y;
        __syncthreads();
    }
    chunkOffs[t] = lds[t] - v;
}

__global__ void k_scan3(int* rowptr, const int* __restrict__ chunkOffs, int n, int e) {
    int i = blockIdx.x * blockDim.x + threadIdx.x;
    if (i < n) rowptr[i] += chunkOffs[i >> 10];
    if (i == 0) rowptr[n] = e;
}

// ---- xs = f16(dinv (x) x) ---------------------------------------------------
template <int F>
__global__ void k_prescale(const float* __restrict__ x, const float* __restrict__ dinv,
                           f16* __restrict__ xs, int n) {
    constexpr int CH = F / 2;
    int idx = blockIdx.x * blockDim.x + threadIdx.x;
    if (idx >= n * CH) return;
    int node = idx / CH;
    int c = idx - node * CH;
    float d = dinv[node];
    float v[2];
    vload<2>(v, x + (long long)node * F + c * 2);
    f16x2 h;
    h[0] = (f16)(v[0] * d);
    h[1] = (f16)(v[1] * d);
    *reinterpret_cast<f16x2*>(xs + (long long)node * F + c * 2) = h;
}

// ---- gather row-sum (fp16 in, fp32 out) ------------------------------------
template <int F>
__global__ __launch_bounds__(256) void k_gather(
        const int* __restrict__ rowptr, const int* __restrict__ eSrc,
        const float* __restrict__ dinv, const f16* __restrict__ hs,
        float* __restrict__ out, int n) {
    constexpr int CH = F / 2;
    int wave = threadIdx.x >> 6;
    int lane = threadIdx.x & 63;
    int node = blockIdx.x * (blockDim.x >> 6) + wave;
    if (node >= n || lane >= CH) return;

    f16x2 sv = *reinterpret_cast<const f16x2*>(hs + (long long)node * F + lane * 2);
    float acc0 = (float)sv[0], acc1 = (float)sv[1];

    int rs = rowptr[node], re = rowptr[node + 1];
    int e = rs;
    for (; e + 8 <= re; e += 8) {
        int s[8];
#pragma unroll
        for (int u = 0; u < 8; u++) s[u] = eSrc[e + u];
        f16x2 v[8];
#pragma unroll
        for (int u = 0; u < 8; u++)
            v[u] = *reinterpret_cast<const f16x2*>(hs + (long long)s[u] * F + lane * 2);
#pragma unroll
        for (int u = 0; u < 8; u++) {
            acc0 += (float)v[u][0];
            acc1 += (float)v[u][1];
        }
    }
    for (; e < re; e++) {
        int s = eSrc[e];
        f16x2 v = *reinterpret_cast<const f16x2*>(hs + (long long)s * F + lane * 2);
        acc0 += (float)v[0];
        acc1 += (float)v[1];
    }
    float di = dinv[node];
    *reinterpret_cast<float2*>(out + (long long)node * F + lane * 2) =
        make_float2(acc0 * di, acc1 * di);
}

// ---- LDS-tiled node GEMM ---------------------------------------------------
template <int K, int FOUT, int VEC, bool RELU, bool SCALE, bool OUTH>
__global__ __launch_bounds__(256) void k_gemm_lds(
        const float* __restrict__ in, const float* __restrict__ W,
        const float* __restrict__ bias, const float* __restrict__ dinv,
        float* __restrict__ outf, f16* __restrict__ outh, int n) {
    constexpr int M = 72, NT = 8, CG = FOUT / VEC;  // CG == 27
    constexpr int LROW = 80;
    constexpr int KV = (K % 4 == 0) ? 4 : 2;
    constexpr int GPN = K / KV;
    constexpr int TOT = GPN * M;
    static_assert(CG == 27, "FOUT must be 27*VEC");

    __shared__ float a_lds[K * LROW];

    int t = threadIdx.x;
    int node0 = blockIdx.x * M;

    for (int it = 0; it < (TOT + 255) / 256; it++) {
        int f = t + it * 256;
        if (f < TOT) {
            int node = f / GPN;
            int kq = f - node * GPN;
            float v[KV] = {};
            if (node0 + node < n)
                vload<KV>(v, in + (long long)(node0 + node) * K + kq * KV);
#pragma unroll
            for (int j = 0; j < KV; j++)
                a_lds[(kq * KV + j) * LROW + node] = v[j];
        }
    }
    __syncthreads();

    if (t >= 243) return;
    int cg = t % 27;
    int strip = t / 27;

    float acc[NT][VEC];
#pragma unroll
    for (int i = 0; i < NT; i++)
#pragma unroll
        for (int j = 0; j < VEC; j++) acc[i][j] = 0.f;

    const float* wp = W + cg * VEC;
    for (int k = 0; k < K; k++) {
        float w[VEC];
        vload<VEC>(w, wp + k * FOUT);
        float av[NT];
        vload<NT>(av, &a_lds[k * LROW + strip * NT]);
#pragma unroll
        for (int i = 0; i < NT; i++)
#pragma unroll
            for (int j = 0; j < VEC; j++) acc[i][j] += av[i] * w[j];
    }

    float bv[VEC];
    vload<VEC>(bv, bias + cg * VEC);
#pragma unroll
    for (int i = 0; i < NT; i++) {
        int node = node0 + strip * NT + i;
        if (node >= n) break;
        float sc = SCALE ? dinv[node] : 1.0f;
        float o[VEC];
#pragma unroll
        for (int j = 0; j < VEC; j++) {
            o[j] = acc[i][j] + bv[j];
            if (RELU) o[j] = fmaxf(o[j], 0.f);
            if (SCALE) o[j] *= sc;
        }
        if constexpr (OUTH) {
            if constexpr (VEC == 2) {
                f16x2 h; h[0] = (f16)o[0]; h[1] = (f16)o[1];
                *reinterpret_cast<f16x2*>(outh + (long long)node * FOUT + cg * VEC) = h;
            } else {
                f16x4 h;
#pragma unroll
                for (int j = 0; j < 4; j++) h[j] = (f16)o[j];
                *reinterpret_cast<f16x4*>(outh + (long long)node * FOUT + cg * VEC) = h;
            }
        } else {
            vstore<VEC>(outf + (long long)node * FOUT + cg * VEC, o);
        }
    }
}

// ---- per-graph boundaries (batch sorted ascending) -------------------------
__global__ void k_init_start(int* start, int n, int g) {
    int i = blockIdx.x * blockDim.x + threadIdx.x;
    if (i <= g) start[i] = n;
}
__global__ void k_find_start(const int* __restrict__ batch, int* start, int n) {
    int i = blockIdx.x * blockDim.x + threadIdx.x;
    if (i >= n) return;
    int b = batch[i];
    int bp = (i == 0) ? -1 : batch[i - 1];
    for (int g = bp + 1; g <= b; g++) start[g] = i;
}

// ---- segmented mean-pool ----------------------------------------------------
template <int F, int NSEG>
__global__ void k_pool(const float* __restrict__ h, const int* __restrict__ start,
                       float* __restrict__ psum) {
    int g = blockIdx.x / NSEG;
    int seg = blockIdx.x - g * NSEG;
    int f = threadIdx.x;
    if (f >= F) return;
    int s = start[g], e = start[g + 1];
    int len = e - s;
    int chunk = (len + NSEG - 1) / NSEG;
    int cs = s + seg * chunk;
    int ce = cs + chunk < e ? cs + chunk : e;
    if (cs >= ce) return;
    float acc = 0.f;
    for (int nd = cs; nd < ce; nd++) acc += h[(long long)nd * F + f];
    atomicAdd(&psum[g * F + f], acc);
}

// ---- FC layers (fc1 folds the mean divide) ---------------------------------
__global__ void k_fc1(const float* __restrict__ P, const int* __restrict__ start,
                      const float* __restrict__ W, const float* __restrict__ bias,
                      float* __restrict__ out) {
    int row = blockIdx.x >> 2;
    int o = (blockIdx.x & 3) * 256 + threadIdx.x;
    int cnt = start[row + 1] - start[row];
    float scale = 1.0f / fmaxf((float)cnt, 1.0f);
    __shared__ float prow[216];
    if (threadIdx.x < 216) prow[threadIdx.x] = P[row * 216 + threadIdx.x] * scale;
    __syncthreads();
    float acc = bias[o];
    for (int k = 0; k < 216; k++) acc += prow[k] * W[k * 1024 + o];
    out[row * 1024 + o] = fmaxf(acc, 0.f);
}
__global__ void k_fc2(const float* __restrict__ G, const float* __restrict__ W,
                      const float* __restrict__ bias, float* __restrict__ out) {
    int row = blockIdx.x;
    int o = threadIdx.x;  // 128
    __shared__ float grow[1024];
    for (int k = threadIdx.x; k < 1024; k += 128) grow[k] = G[row * 1024 + k];
    __syncthreads();
    float acc = bias[o];
    for (int k = 0; k < 1024; k++) acc += grow[k] * W[k * 128 + o];
    out[row * 128 + o] = acc;
}

// ---------------------------------------------------------------------------
extern "C" void kernel_launch(void* const* d_in, const int* in_sizes, int n_in,
                              void* d_out, int out_size, void* d_ws, size_t ws_size,
                              hipStream_t stream) {
    const float* x     = (const float*)d_in[0];
    const int*   ei    = (const int*)d_in[1];
    const int*   batch = (const int*)d_in[2];
    const float* W1  = (const float*)d_in[3];
    const float* b1  = (const float*)d_in[4];
    const float* W2  = (const float*)d_in[5];
    const float* b2  = (const float*)d_in[6];
    const float* W3  = (const float*)d_in[7];
    const float* b3  = (const float*)d_in[8];
    const float* Wf1 = (const float*)d_in[9];
    const float* bf1 = (const float*)d_in[10];
    const float* Wf2 = (const float*)d_in[11];
    const float* bf2 = (const float*)d_in[12];
    float* out = (float*)d_out;

    const int N = in_sizes[0] / 54;   // 100000
    const int E = in_sizes[1] / 2;    // 1600000
    const int G = 256;
    const int* row = ei;
    const int* col = ei + E;
    const int NCHUNK = cdiv(N, 1024);
    const int NB = cdiv(N, BSPAN);    // 196 buckets
    const int NBLK_A = cdiv(E, EPB);  // 391 partition blocks

    // workspace carve-up (256B aligned)
    char* ws = (char*)d_ws;
    size_t off = 0;
    auto carve = [&](size_t bytes) {
        void* p = ws + off;
        off += (bytes + 255) & ~(size_t)255;
        return p;
    };
    int*   counts    = (int*)carve((size_t)N * 4);
    int*   rowptr    = (int*)carve((size_t)(N + 1) * 4);
    int*   chunkSums = (int*)carve(128 * 4);
    int*   chunkOffs = (int*)carve(128 * 4);
    int*   bktCnt    = (int*)carve(256 * 4);
    int*   bktOff    = (int*)carve(257 * 4);
    int*   bktCur    = (int*)carve(256 * 4);
    int*   eSrc      = (int*)carve((size_t)E * 4);
    float* dinv      = (float*)carve((size_t)N * 4);
    f16*   xs        = (f16*)carve((size_t)N * 54 * 2);
    f16*   hsbuf     = (f16*)carve((size_t)N * 108 * 2);   // fp16 gemm outputs
    float* bufA      = (float*)carve((size_t)N * 108 * 4); // fp32 gather outputs
    float* bufB      = (float*)carve((size_t)N * 216 * 4); // fp32 h3 (86.4 MB)
    float* psum      = (float*)carve((size_t)G * 216 * 4);
    float* gbuf      = (float*)carve((size_t)G * 1024 * 4);
    int*   start     = (int*)carve((size_t)(G + 1) * 4);

    // ebuf (12.8 MB) aliases bufB: only live before the layer pipeline starts.
    int2* ebuf = (int2*)bufB;

    const int T = 256;

    // ---- bucketed CSR build: hist -> scan -> partition -> count -> fill ----
    k_zero2<<<cdiv(G * 216, T), T, 0, stream>>>(psum, G * 216, bktCnt, 256);
    k_bkt_hist<<<NBLK_A, 256, 0, stream>>>(col, bktCnt, E, NB);
    k_bkt_scan<<<1, 256, 0, stream>>>(bktCnt, bktOff, bktCur, NB, E);
    k_bkt_part<<<NBLK_A, 256, 0, stream>>>(row, col, bktCur, ebuf, E, NB);
    k_bkt_count<<<NB, 256, 0, stream>>>(ebuf, bktOff, counts, dinv, N);
    k_scan1<<<NCHUNK, 256, 0, stream>>>(counts, rowptr, chunkSums, N);
    k_scan2<<<1, 128, 0, stream>>>(chunkSums, chunkOffs, NCHUNK);
    k_scan3<<<cdiv(N, T), T, 0, stream>>>(rowptr, chunkOffs, N, E);
    k_bkt_fill<<<NB, 256, 0, stream>>>(ebuf, bktOff, rowptr, eSrc, N);
    k_prescale<54><<<cdiv(N * 27, T), T, 0, stream>>>(x, dinv, xs, N);

    // ---- graph boundaries ----
    k_init_start<<<cdiv(G + 1, T), T, 0, stream>>>(start, N, G);
    k_find_start<<<cdiv(N, T), T, 0, stream>>>(batch, start, N);

    const int GB = cdiv(N, 72);

    // ---- layer 1: a1 = A_hat x ; hs1 = f16(dinv*relu(a1@W1 + b1)) ----
    k_gather<54><<<cdiv(N, 4), 256, 0, stream>>>(rowptr, eSrc, dinv, xs, bufA, N);
    k_gemm_lds<54, 54, 2, true, true, true><<<GB, 256, 0, stream>>>(bufA, W1, b1, dinv, nullptr, hsbuf, N);

    // ---- layer 2: a2 = A_hat h1 ; hs2 = f16(dinv*relu(a2@W2 + b2)) ----
    k_gather<54><<<cdiv(N, 4), 256, 0, stream>>>(rowptr, eSrc, dinv, hsbuf, bufA, N);
    k_gemm_lds<54, 108, 4, true, true, true><<<GB, 256, 0, stream>>>(bufA, W2, b2, dinv, nullptr, hsbuf, N);

    // ---- layer 3: a3 = A_hat h2 ; h3 = relu(a3@W3 + b3) (fp32) ----
    k_gather<108><<<cdiv(N, 4), 256, 0, stream>>>(rowptr, eSrc, dinv, hsbuf, bufA, N);
    k_gemm_lds<108, 216, 8, true, false, false><<<GB, 256, 0, stream>>>(bufA, W3, b3, nullptr, bufB, nullptr, N);

    // ---- mean pool (segmented) + FC head ----
    k_pool<216, 4><<<G * 4, T, 0, stream>>>(bufB, start, psum);
    k_fc1<<<G * 4, T, 0, stream>>>(psum, start, Wf1, bf1, gbuf);
    k_fc2<<<G, 128, 0, stream>>>(gbuf, Wf2, bf2, out);
}